// Round 7
// baseline (845.079 us; speedup 1.0000x reference)
//
#include <hip/hip_runtime.h>
#include <hip/hip_bf16.h>

#define DIM  2048
#define DFF  8192
#define NH   32
#define HD   64
#define TT   2048
#define MM   4096   // B*T

typedef __attribute__((ext_vector_type(4))) float f32x4;
typedef __attribute__((ext_vector_type(4))) unsigned int u32x4;
typedef __attribute__((ext_vector_type(2))) unsigned int u32x2;
typedef unsigned short ushort_t;

// D = A*B + D, bf16 16x16x32 (VGPR acc)
#define MFMA16(ACC, A, B) \
  asm volatile("v_mfma_f32_16x16x32_bf16 %0, %1, %2, %0" : "+v"(ACC) : "v"(A), "v"(B))

// async global->LDS, 16B per lane (dest = wave-uniform base + lane*16)
#define GL16(GP, LP)                                                     \
  __builtin_amdgcn_global_load_lds(                                      \
      (const __attribute__((address_space(1))) void*)(GP),               \
      (__attribute__((address_space(3))) void*)(LP), 16, 0, 0)

__device__ __forceinline__ unsigned int f2bu(float f) {
  union { __hip_bfloat16 h; unsigned short u; } c;
  c.h = __float2bfloat16(f);
  return (unsigned int)c.u;
}
// 2^x via native transcendental
__device__ __forceinline__ float fexp2(float x) {
  float r; asm("v_exp_f32 %0, %1" : "=v"(r) : "v"(x)); return r;
}
// pack two f32 -> bf16x2 in one instr (no builtin on gfx950)
__device__ __forceinline__ unsigned cvtpk(float lo, float hi) {
  unsigned r; asm("v_cvt_pk_bf16_f32 %0, %1, %2" : "=v"(r) : "v"(lo), "v"(hi));
  return r;
}
__device__ __forceinline__ float fmax3(float a, float b, float c) {
  float r; asm("v_max3_f32 %0, %1, %2, %3" : "=v"(r) : "v"(a), "v"(b), "v"(c));
  return r;
}

// ---------------------------------------------------------------------------
// Transpose + fp32->bf16 convert: in[R,C] fp32 -> out[C,R] bf16
// ---------------------------------------------------------------------------
__global__ __launch_bounds__(256)
void transpose_cvt(const float* __restrict__ in, __hip_bfloat16* __restrict__ out,
                   int R, int C) {
  __shared__ float tile[32][33];
  const int tx = threadIdx.x, ty = threadIdx.y;       // (32, 8)
  const int bx = blockIdx.x * 32, by = blockIdx.y * 32;
#pragma unroll
  for (int i = 0; i < 32; i += 8)
    tile[ty + i][tx] = in[(size_t)(by + ty + i) * C + bx + tx];
  __syncthreads();
#pragma unroll
  for (int i = 0; i < 32; i += 8)
    out[(size_t)(bx + ty + i) * R + by + tx] = __float2bfloat16(tile[tx][ty + i]);
}

// ---------------------------------------------------------------------------
// LayerNorm: fp32 [rows, 2048] -> bf16, one block (256 thr) per row
// ---------------------------------------------------------------------------
__global__ __launch_bounds__(256)
void ln_kernel(const float* __restrict__ in, const float* __restrict__ gw,
               const float* __restrict__ bw, __hip_bfloat16* __restrict__ out) {
  const int row = blockIdx.x;
  const int t = threadIdx.x;
  const float* x = in + (size_t)row * DIM;
  const float4 v0 = ((const float4*)x)[t * 2];
  const float4 v1 = ((const float4*)x)[t * 2 + 1];
  float s  = v0.x + v0.y + v0.z + v0.w + v1.x + v1.y + v1.z + v1.w;
  float ss = v0.x*v0.x + v0.y*v0.y + v0.z*v0.z + v0.w*v0.w
           + v1.x*v1.x + v1.y*v1.y + v1.z*v1.z + v1.w*v1.w;
#pragma unroll
  for (int o = 32; o >= 1; o >>= 1) { s += __shfl_xor(s, o); ss += __shfl_xor(ss, o); }
  __shared__ float red[8];
  if ((t & 63) == 0) { red[t >> 6] = s; red[4 + (t >> 6)] = ss; }
  __syncthreads();
  s  = red[0] + red[1] + red[2] + red[3];
  ss = red[4] + red[5] + red[6] + red[7];
  const float mean = s * (1.0f / DIM);
  const float rstd = rsqrtf(ss * (1.0f / DIM) - mean * mean + 1e-5f);
  const float4 g0 = ((const float4*)gw)[t * 2], g1 = ((const float4*)gw)[t * 2 + 1];
  const float4 b0 = ((const float4*)bw)[t * 2], b1 = ((const float4*)bw)[t * 2 + 1];
  uint4 o;
  o.x = f2bu((v0.x - mean) * rstd * g0.x + b0.x) | (f2bu((v0.y - mean) * rstd * g0.y + b0.y) << 16);
  o.y = f2bu((v0.z - mean) * rstd * g0.z + b0.z) | (f2bu((v0.w - mean) * rstd * g0.w + b0.w) << 16);
  o.z = f2bu((v1.x - mean) * rstd * g1.x + b1.x) | (f2bu((v1.y - mean) * rstd * g1.y + b1.y) << 16);
  o.w = f2bu((v1.z - mean) * rstd * g1.z + b1.z) | (f2bu((v1.w - mean) * rstd * g1.w + b1.w) << 16);
  *(uint4*)((char*)out + ((size_t)row * DIM + t * 8) * 2) = o;
}

// ---------------------------------------------------------------------------
// 128x128-tile GEMM, m97 structure (PROVEN ~700-900 TF class this session):
// BK=32, 4 waves (2x2), 64x64/wave, 16 KB LDS -> many blocks/CU, compiler
// waits + implicit multi-block overlap (m114).  1D grid + bijective XCD
// swizzle (T1).  C = A[M,K] * Bt[N,K]^T + bias, templated epilogue:
//  EPI 0: QKV scatter -> Q(*1/8*log2e)/K [B,H,T,D] bf16, V -> [B,H,D,T] bf16
//  EPI 1: + res -> fp32 out       (O-proj + residual)
//  EPI 2: gelu(erf) -> bf16 out   (FFN1)
//  EPI 3: + res -> fp32 out       (FFN2 + residual, final output)
// ---------------------------------------------------------------------------
template <int EPI>
__global__ __launch_bounds__(256)
void gemm_bt(const __hip_bfloat16* __restrict__ A, const __hip_bfloat16* __restrict__ Bt,
             const float* __restrict__ bias, const float* __restrict__ res,
             void* __restrict__ o0, void* __restrict__ o1, void* __restrict__ o2,
             int M, int N, int K) {
  __shared__ __hip_bfloat16 As[128 * 32];
  __shared__ __hip_bfloat16 Bs[128 * 32];
  const int tid = threadIdx.x;
  const int l = tid & 63, w = tid >> 6;
  const int wr = w >> 1, wc = w & 1;
  const int g = l >> 4, q15 = l & 15;

  const int nby = M >> 7;
  const int nwg = (N >> 7) * nby;
  int id = blockIdx.x;
  { // bijective XCD swizzle (nwg % 8 == 0 for all our shapes)
    const int cpx = nwg >> 3;
    id = (id & 7) * cpx + (id >> 3);
  }
  const int bm = (id % nby) << 7;
  const int bn = (id / nby) << 7;

  f32x4 acc[4][4];
#pragma unroll
  for (int a = 0; a < 4; ++a)
#pragma unroll
    for (int b = 0; b < 4; ++b) acc[a][b] = (f32x4)0.0f;

  const __hip_bfloat16* aSrc = A  + (size_t)(bm + (tid >> 2)) * K + (tid & 3) * 8;
  const __hip_bfloat16* bSrc = Bt + (size_t)(bn + (tid >> 2)) * K + (tid & 3) * 8;
  __hip_bfloat16* aDst = As + tid * 8;
  __hip_bfloat16* bDst = Bs + tid * 8;
  const size_t rowStep = (size_t)64 * K;

  for (int kt = 0; kt < K; kt += 32) {
    GL16(aSrc + kt,            aDst);
    GL16(aSrc + rowStep + kt,  aDst + 2048);
    GL16(bSrc + kt,            bDst);
    GL16(bSrc + rowStep + kt,  bDst + 2048);
    __syncthreads();
    u32x4 af[4], bf[4];
#pragma unroll
    for (int rb = 0; rb < 4; ++rb)
      af[rb] = *(const u32x4*)(As + (wr * 64 + rb * 16 + q15) * 32 + g * 8);
#pragma unroll
    for (int cb = 0; cb < 4; ++cb)
      bf[cb] = *(const u32x4*)(Bs + (wc * 64 + cb * 16 + q15) * 32 + g * 8);
#pragma unroll
    for (int rb = 0; rb < 4; ++rb)
#pragma unroll
      for (int cb = 0; cb < 4; ++cb) MFMA16(acc[rb][cb], af[rb], bf[cb]);
    __syncthreads();
  }

#pragma unroll
  for (int rb = 0; rb < 4; ++rb) {
    const int row0 = bm + wr * 64 + rb * 16 + g * 4;
#pragma unroll
    for (int cb = 0; cb < 4; ++cb) {
      const int col = bn + wc * 64 + cb * 16 + q15;
      const float bv = bias[col];
#pragma unroll
      for (int i = 0; i < 4; ++i) {
        const int m = row0 + i;
        float v = acc[rb][cb][i] + bv;
        if constexpr (EPI == 0) {
          const int sel = col >> 11, hd = col & 2047, h = hd >> 6, d = hd & 63;
          const int b = m >> 11, t = m & 2047;
          if (sel == 0) {
            // fold 1/sqrt(64) * log2(e) into Q (softmax runs in exp2 domain)
            ((__hip_bfloat16*)o0)[((size_t)(b * NH + h) * TT + t) * HD + d] =
                __float2bfloat16(v * 0.18033688011112042f);
          } else if (sel == 1) {
            ((__hip_bfloat16*)o1)[((size_t)(b * NH + h) * TT + t) * HD + d] =
                __float2bfloat16(v);
          } else {
            ((__hip_bfloat16*)o2)[((size_t)(b * NH + h) * HD + d) * TT + t] =
                __float2bfloat16(v);  // V transposed: [B,H,D,T]
          }
        } else if constexpr (EPI == 1) {
          ((float*)o0)[(size_t)m * N + col] = v + res[(size_t)m * N + col];
        } else if constexpr (EPI == 2) {
          ((__hip_bfloat16*)o0)[(size_t)m * N + col] =
              __float2bfloat16(0.5f * v * (1.0f + erff(v * 0.70710678118654752f)));
        } else {
          ((float*)o0)[(size_t)m * N + col] = v + res[(size_t)m * N + col];
        }
      }
    }
  }
}

// ---------------------------------------------------------------------------
// Flash attention.  VALU-trimmed softmax: exp2-domain scores (log2e folded
// into Q), v_cvt_pk_bf16_f32 packing, defer-max (THR=8, log2 units), v_max3
// row-max tree, K-tile register prefetch, setprio around MFMA clusters.
// ---------------------------------------------------------------------------
__global__ __launch_bounds__(256)
void attn_kernel(const __hip_bfloat16* __restrict__ Q, const __hip_bfloat16* __restrict__ Kx,
                 const __hip_bfloat16* __restrict__ Vt, __hip_bfloat16* __restrict__ out) {
  __shared__ unsigned int Plds[4][2048];  // 8KB per wave
  const int tid = threadIdx.x;
  const int l = tid & 63, w = tid >> 6;
  const int g = l >> 4, q15 = l & 15;
  const int bh = blockIdx.x >> 3;
  const int q0 = (blockIdx.x & 7) * 256 + w * 64;
  const __hip_bfloat16* Qb = Q  + (size_t)bh * TT * HD;
  const __hip_bfloat16* Kb = Kx + (size_t)bh * TT * HD;
  const __hip_bfloat16* Vb = Vt + (size_t)bh * HD * TT;
  unsigned int* Pw = Plds[w];

  u32x4 qf[4][2];
#pragma unroll
  for (int rb = 0; rb < 4; ++rb)
#pragma unroll
    for (int ks = 0; ks < 2; ++ks)
      qf[rb][ks] = *(const u32x4*)(Qb + (size_t)(q0 + rb * 16 + q15) * HD + ks * 32 + g * 8);

  f32x4 acc[4][4];  // [db][rb]
#pragma unroll
  for (int a = 0; a < 4; ++a)
#pragma unroll
    for (int b = 0; b < 4; ++b) acc[a][b] = (f32x4)0.0f;
  float mstat[4] = {-3e38f, -3e38f, -3e38f, -3e38f};
  float lstat[4] = {0.f, 0.f, 0.f, 0.f};

  u32x4 kf[2][4];
#pragma unroll
  for (int cb = 0; cb < 4; ++cb)
#pragma unroll
    for (int ks = 0; ks < 2; ++ks)
      kf[ks][cb] = *(const u32x4*)(Kb + (size_t)(cb * 16 + q15) * HD + ks * 32 + g * 8);

  for (int s0 = 0; s0 < TT; s0 += 64) {
    f32x4 st[4][4];  // [cb][rb] = S^T (exp2-domain logits)
#pragma unroll
    for (int a = 0; a < 4; ++a)
#pragma unroll
      for (int b = 0; b < 4; ++b) st[a][b] = (f32x4)0.0f;
    __builtin_amdgcn_s_setprio(1);
#pragma unroll
    for (int ks = 0; ks < 2; ++ks)
#pragma unroll
      for (int cb = 0; cb < 4; ++cb)
#pragma unroll
        for (int rb = 0; rb < 4; ++rb) MFMA16(st[cb][rb], kf[ks][cb], qf[rb][ks]);
    __builtin_amdgcn_s_setprio(0);
    // prefetch next K tile (kf dead after QK^T) — hides under softmax+PV
    if (s0 + 64 < TT) {
#pragma unroll
      for (int cb = 0; cb < 4; ++cb)
#pragma unroll
        for (int ks = 0; ks < 2; ++ks)
          kf[ks][cb] = *(const u32x4*)(Kb + (size_t)(s0 + 64 + cb * 16 + q15) * HD + ks * 32 + g * 8);
    }
#pragma unroll
    for (int rb = 0; rb < 4; ++rb) {
      // row-max tree (v_max3)
      float a0 = fmax3(st[0][rb][0], st[0][rb][1], st[0][rb][2]);
      float a1 = fmax3(st[0][rb][3], st[1][rb][0], st[1][rb][1]);
      float a2 = fmax3(st[1][rb][2], st[1][rb][3], st[2][rb][0]);
      float a3 = fmax3(st[2][rb][1], st[2][rb][2], st[2][rb][3]);
      float a4 = fmax3(st[3][rb][0], st[3][rb][1], st[3][rb][2]);
      float pm = fmax3(fmax3(a0, a1, a2), a3, fmax3(a4, st[3][rb][3], a0));
      pm = fmaxf(pm, __shfl_xor(pm, 16));
      pm = fmaxf(pm, __shfl_xor(pm, 32));
      // defer-max: only rescale when the running max grows by > 8 (log2)
      if (!__all(pm <= mstat[rb] + 8.0f)) {
        const float mnew = fmaxf(mstat[rb], pm);
        const float corr = fexp2(mstat[rb] - mnew);
        mstat[rb] = mnew;
        lstat[rb] *= corr;
#pragma unroll
        for (int db = 0; db < 4; ++db)
#pragma unroll
          for (int i = 0; i < 4; ++i) acc[db][rb][i] *= corr;
      }
      const float mcur = mstat[rb];
      float rs = 0.f;
      const int row = rb * 16 + q15;
      const int rx = row & 7;
#pragma unroll
      for (int cb = 0; cb < 4; ++cb) {
        const float p0 = fexp2(st[cb][rb][0] - mcur);
        const float p1 = fexp2(st[cb][rb][1] - mcur);
        const float p2 = fexp2(st[cb][rb][2] - mcur);
        const float p3 = fexp2(st[cb][rb][3] - mcur);
        rs += (p0 + p1) + (p2 + p3);
        const int seg = (cb * 2 + (g >> 1)) ^ rx;
        u32x2 pk = {cvtpk(p0, p1), cvtpk(p2, p3)};
        *(u32x2*)(Pw + row * 32 + seg * 4 + (g & 1) * 2) = pk;
      }
      rs += __shfl_xor(rs, 16);
      rs += __shfl_xor(rs, 32);
      lstat[rb] += rs;
    }
    // V loads batched (independent of P write settling)
    u32x4 vf[2][4];
#pragma unroll
    for (int ks2 = 0; ks2 < 2; ++ks2)
#pragma unroll
      for (int db = 0; db < 4; ++db)
        vf[ks2][db] = *(const u32x4*)(Vb + (size_t)(db * 16 + q15) * TT + s0 + ks2 * 32 + g * 8);
    u32x4 pf[2][4];
#pragma unroll
    for (int ks2 = 0; ks2 < 2; ++ks2)
#pragma unroll
      for (int rb = 0; rb < 4; ++rb) {
        const int row = rb * 16 + q15;
        const int seg = (ks2 * 4 + g) ^ (row & 7);
        pf[ks2][rb] = *(const u32x4*)(Pw + row * 32 + seg * 4);
      }
    __builtin_amdgcn_s_setprio(1);
#pragma unroll
    for (int ks2 = 0; ks2 < 2; ++ks2)
#pragma unroll
      for (int db = 0; db < 4; ++db)
#pragma unroll
        for (int rb = 0; rb < 4; ++rb) MFMA16(acc[db][rb], vf[ks2][db], pf[ks2][rb]);
    __builtin_amdgcn_s_setprio(0);
  }
  const int b = bh >> 5, hh = bh & 31;
#pragma unroll
  for (int rb = 0; rb < 4; ++rb) {
    const float inv = 1.0f / lstat[rb];
    const size_t trow = (size_t)(b * TT + q0 + rb * 16 + q15);
#pragma unroll
    for (int db = 0; db < 4; ++db) {
      u32x2 pk = {cvtpk(acc[db][rb][0] * inv, acc[db][rb][1] * inv),
                  cvtpk(acc[db][rb][2] * inv, acc[db][rb][3] * inv)};
      *(u32x2*)(out + trow * DIM + hh * 64 + db * 16 + g * 4) = pk;
    }
  }
}

// ---------------------------------------------------------------------------
extern "C" void kernel_launch(void* const* d_in, const int* in_sizes, int n_in,
                              void* d_out, int out_size, void* d_ws, size_t ws_size,
                              hipStream_t stream) {
  (void)in_sizes; (void)n_in; (void)out_size; (void)ws_size;
  const float* x     = (const float*)d_in[0];
  const float* w_qkv = (const float*)d_in[1];
  const float* b_qkv = (const float*)d_in[2];
  const float* w_o   = (const float*)d_in[3];
  const float* b_o   = (const float*)d_in[4];
  const float* g1    = (const float*)d_in[5];
  const float* be1   = (const float*)d_in[6];
  const float* w1    = (const float*)d_in[7];
  const float* b1    = (const float*)d_in[8];
  const float* w2    = (const float*)d_in[9];
  const float* b2    = (const float*)d_in[10];
  const float* g2    = (const float*)d_in[11];
  const float* be2   = (const float*)d_in[12];

  char* ws = (char*)d_ws;
  size_t off = 0;
  auto alloc = [&](size_t bytes) {
    void* p = ws + off;
    off += (bytes + 255) & ~(size_t)255;
    return p;
  };
  __hip_bfloat16* WqkvT = (__hip_bfloat16*)alloc((size_t)6144 * 2048 * 2);  // 24MB
  __hip_bfloat16* WoT   = (__hip_bfloat16*)alloc((size_t)2048 * 2048 * 2);  //  8MB
  __hip_bfloat16* W1T   = (__hip_bfloat16*)alloc((size_t)8192 * 2048 * 2);  // 32MB
  __hip_bfloat16* W2T   = (__hip_bfloat16*)alloc((size_t)2048 * 8192 * 2);  // 32MB
  __hip_bfloat16* hbuf  = (__hip_bfloat16*)alloc((size_t)MM * DIM * 2);
  float*          xres  = (float*)alloc((size_t)MM * DIM * 4);
  __hip_bfloat16* Qb    = (__hip_bfloat16*)alloc((size_t)MM * DIM * 2);
  __hip_bfloat16* Kb    = (__hip_bfloat16*)alloc((size_t)MM * DIM * 2);
  __hip_bfloat16* Vtb   = (__hip_bfloat16*)alloc((size_t)MM * DIM * 2);
  __hip_bfloat16* attno = (__hip_bfloat16*)alloc((size_t)MM * DIM * 2);
  __hip_bfloat16* f1    = Qb;  // FFN hidden (67.1MB) aliases Qb..attno (dead)

  const dim3 tb(32, 8);
  transpose_cvt<<<dim3(6144 / 32, 2048 / 32), tb, 0, stream>>>(w_qkv, WqkvT, 2048, 6144);
  transpose_cvt<<<dim3(2048 / 32, 2048 / 32), tb, 0, stream>>>(w_o, WoT, 2048, 2048);
  transpose_cvt<<<dim3(8192 / 32, 2048 / 32), tb, 0, stream>>>(w1, W1T, 2048, 8192);
  transpose_cvt<<<dim3(2048 / 32, 8192 / 32), tb, 0, stream>>>(w2, W2T, 8192, 2048);

  ln_kernel<<<MM, 256, 0, stream>>>(x, g1, be1, hbuf);
  // QKV: 32x48 = 1536 blocks (6 exact rounds)
  gemm_bt<0><<<(MM / 128) * (6144 / 128), 256, 0, stream>>>(
      hbuf, WqkvT, b_qkv, nullptr, Qb, Kb, Vtb, MM, 6144, 2048);
  attn_kernel<<<512, 256, 0, stream>>>(Qb, Kb, Vtb, attno);
  // O-proj: 512 blocks (2 exact rounds)
  gemm_bt<1><<<(MM / 128) * (2048 / 128), 256, 0, stream>>>(
      attno, WoT, b_o, x, xres, nullptr, nullptr, MM, 2048, 2048);
  ln_kernel<<<MM, 256, 0, stream>>>(xres, g2, be2, hbuf);
  // FFN1: 2048 blocks (8 exact rounds)
  gemm_bt<2><<<(MM / 128) * (8192 / 128), 256, 0, stream>>>(
      hbuf, W1T, b1, nullptr, f1, nullptr, nullptr, MM, 8192, 2048);
  // FFN2: 512 blocks (2 exact rounds), K=8192, fused +res -> d_out
  gemm_bt<3><<<(MM / 128) * (2048 / 128), 256, 0, stream>>>(
      f1, W2T, b2, xres, d_out, nullptr, nullptr, MM, 2048, 8192);
}

// Round 8
// 716.809 us; speedup vs baseline: 1.1789x; 1.1789x over previous
//
#include <hip/hip_runtime.h>
#include <hip/hip_bf16.h>

#define DIM  2048
#define DFF  8192
#define NH   32
#define HD   64
#define TT   2048
#define MM   4096   // B*T

typedef __attribute__((ext_vector_type(4))) float f32x4;
typedef __attribute__((ext_vector_type(4))) unsigned int u32x4;
typedef __attribute__((ext_vector_type(2))) unsigned int u32x2;
typedef unsigned short ushort_t;

// D = A*B + D, bf16 16x16x32 (VGPR acc)
#define MFMA16(ACC, A, B) \
  asm volatile("v_mfma_f32_16x16x32_bf16 %0, %1, %2, %0" : "+v"(ACC) : "v"(A), "v"(B))
// AGPR-accumulator variant (gemm256: keeps 128-float acc pinned in AGPRs)
#define MFMA16A(ACC, A, B) \
  asm volatile("v_mfma_f32_16x16x32_bf16 %0, %1, %2, %0" : "+a"(ACC) : "v"(A), "v"(B))

// async global->LDS, 16B per lane (dest = wave-uniform base + lane*16)
#define GL16(GP, LP)                                                     \
  __builtin_amdgcn_global_load_lds(                                      \
      (const __attribute__((address_space(1))) void*)(GP),               \
      (__attribute__((address_space(3))) void*)(LP), 16, 0, 0)

// Hand waitcnt WITHOUT a "memory" clobber (a clobbered asm re-introduces the
// compiler's own vmcnt(0) drain).  Placement pinned with sched_barrier(0).
#define VM(N) do{ asm volatile("s_waitcnt vmcnt(" #N ")");               \
                  __builtin_amdgcn_sched_barrier(0); }while(0)
#define NOOP  ((void)0)

// opaque ds_read_b128 (invisible to SIInsertWaitcnts' LDS-DMA alias check)
template <int IMM>
__device__ __forceinline__ u32x4 dsr(unsigned a) {
  u32x4 d;
  asm volatile("ds_read_b128 %0, %1 offset:%2" : "=v"(d) : "v"(a), "i"(IMM));
  return d;
}

__device__ __forceinline__ unsigned int f2bu(float f) {
  union { __hip_bfloat16 h; unsigned short u; } c;
  c.h = __float2bfloat16(f);
  return (unsigned int)c.u;
}
// 2^x via native transcendental
__device__ __forceinline__ float fexp2(float x) {
  float r; asm("v_exp_f32 %0, %1" : "=v"(r) : "v"(x)); return r;
}
// pack two f32 -> bf16x2 in one instr (no builtin on gfx950)
__device__ __forceinline__ unsigned cvtpk(float lo, float hi) {
  unsigned r; asm("v_cvt_pk_bf16_f32 %0, %1, %2" : "=v"(r) : "v"(lo), "v"(hi));
  return r;
}
__device__ __forceinline__ float fmax3(float a, float b, float c) {
  float r; asm("v_max3_f32 %0, %1, %2, %3" : "=v"(r) : "v"(a), "v"(b), "v"(c));
  return r;
}

// ---------------------------------------------------------------------------
// Transpose + fp32->bf16 convert: in[R,C] fp32 -> out[C,R] bf16
// ---------------------------------------------------------------------------
__global__ __launch_bounds__(256)
void transpose_cvt(const float* __restrict__ in, __hip_bfloat16* __restrict__ out,
                   int R, int C) {
  __shared__ float tile[32][33];
  const int tx = threadIdx.x, ty = threadIdx.y;       // (32, 8)
  const int bx = blockIdx.x * 32, by = blockIdx.y * 32;
#pragma unroll
  for (int i = 0; i < 32; i += 8)
    tile[ty + i][tx] = in[(size_t)(by + ty + i) * C + bx + tx];
  __syncthreads();
#pragma unroll
  for (int i = 0; i < 32; i += 8)
    out[(size_t)(bx + ty + i) * R + by + tx] = __float2bfloat16(tile[tx][ty + i]);
}

// ---------------------------------------------------------------------------
// LayerNorm: fp32 [rows, 2048] -> bf16, one block (256 thr) per row
// ---------------------------------------------------------------------------
__global__ __launch_bounds__(256)
void ln_kernel(const float* __restrict__ in, const float* __restrict__ gw,
               const float* __restrict__ bw, __hip_bfloat16* __restrict__ out) {
  const int row = blockIdx.x;
  const int t = threadIdx.x;
  const float* x = in + (size_t)row * DIM;
  const float4 v0 = ((const float4*)x)[t * 2];
  const float4 v1 = ((const float4*)x)[t * 2 + 1];
  float s  = v0.x + v0.y + v0.z + v0.w + v1.x + v1.y + v1.z + v1.w;
  float ss = v0.x*v0.x + v0.y*v0.y + v0.z*v0.z + v0.w*v0.w
           + v1.x*v1.x + v1.y*v1.y + v1.z*v1.z + v1.w*v1.w;
#pragma unroll
  for (int o = 32; o >= 1; o >>= 1) { s += __shfl_xor(s, o); ss += __shfl_xor(ss, o); }
  __shared__ float red[8];
  if ((t & 63) == 0) { red[t >> 6] = s; red[4 + (t >> 6)] = ss; }
  __syncthreads();
  s  = red[0] + red[1] + red[2] + red[3];
  ss = red[4] + red[5] + red[6] + red[7];
  const float mean = s * (1.0f / DIM);
  const float rstd = rsqrtf(ss * (1.0f / DIM) - mean * mean + 1e-5f);
  const float4 g0 = ((const float4*)gw)[t * 2], g1 = ((const float4*)gw)[t * 2 + 1];
  const float4 b0 = ((const float4*)bw)[t * 2], b1 = ((const float4*)bw)[t * 2 + 1];
  uint4 o;
  o.x = f2bu((v0.x - mean) * rstd * g0.x + b0.x) | (f2bu((v0.y - mean) * rstd * g0.y + b0.y) << 16);
  o.y = f2bu((v0.z - mean) * rstd * g0.z + b0.z) | (f2bu((v0.w - mean) * rstd * g0.w + b0.w) << 16);
  o.z = f2bu((v1.x - mean) * rstd * g1.x + b1.x) | (f2bu((v1.y - mean) * rstd * g1.y + b1.y) << 16);
  o.w = f2bu((v1.z - mean) * rstd * g1.z + b1.z) | (f2bu((v1.w - mean) * rstd * g1.w + b1.w) << 16);
  *(uint4*)((char*)out + ((size_t)row * DIM + t * 8) * 2) = o;
}

// ---------------------------------------------------------------------------
// 256x256 tile, BK=64, 8 waves (2M x 4N), deep-pipelined 4-phase/K-tile,
// 2 K-tiles per loop iteration (literal dbuf indices).  Opaque ds_read +
// no-clobber hand vmcnt ledger: steady vmcnt(10) @ end-ph1, vmcnt(8) @
// end-ph3, tail 8 -> 2 -> 0.
// EPI 0: QKV scatter (Q scaled by 1/8*log2e); EPI 2: gelu; EPI 4: split-K
// ---------------------------------------------------------------------------
template <int EPI>
__global__ __launch_bounds__(512, 2)
void gemm256(const __hip_bfloat16* __restrict__ Abf, const __hip_bfloat16* __restrict__ Btbf,
             const float* __restrict__ bias, const float* __restrict__ res,
             void* __restrict__ o0, void* __restrict__ o1, void* __restrict__ o2,
             int M, int N, int K, int nkt) {
  __shared__ ushort_t lds[2][2][16384];   // [dbuf][A=0/B=1][256*64] = 128 KiB
  const int tid = threadIdx.x;
  const int l = tid & 63, w = tid >> 6;
  const int wm = w >> 2, wn = w & 3;
  const int g = l >> 4, q15 = l & 15;

  const int nby = M >> 8;
  const int nwg = (N >> 8) * nby;
  int id = blockIdx.x;
  { // bijective XCD swizzle (m204)
    const int qq = nwg >> 3, rr = nwg & 7;
    const int xcd = id & 7, pos = id >> 3;
    id = (xcd < rr ? xcd * (qq + 1) : rr * (qq + 1) + (xcd - rr) * qq) + pos;
  }
  const int bm = (id % nby) << 8;
  const int bn = (id / nby) << 8;
  const int k0 = (EPI == 4) ? (int)blockIdx.y * (nkt << 6) : 0;

  // staging: linear LDS dest + inverse-swizzled global source (rule #21)
  const ushort_t* Au = (const ushort_t*)Abf;
  const ushort_t* Bu = (const ushort_t*)Btbf;
  const int sr = tid >> 3;                         // row within 64-row group
  const int sc = (((tid & 7) ^ (sr & 7)) << 3);    // swizzled col (elements)
  const ushort_t* aBase = Au + (size_t)(bm + sr) * K + (k0 + sc);
  const ushort_t* bBase = Bu + (size_t)(bn + sr) * K + (k0 + sc);
  const int dOff = (w << 9) + (l << 3);            // element off within group

#define SA(BUF, GRP, KT_)                                                \
  GL16(aBase + (size_t)((GRP) << 6) * K + ((KT_) << 6),                  \
       &lds[BUF][0][((GRP) << 12) + dOff])
#define SB(BUF, GRP, KT_)                                                \
  GL16(bBase + (size_t)((GRP) << 6) * K + ((KT_) << 6),                  \
       &lds[BUF][1][((GRP) << 12) + dOff])

  const unsigned lbase =
      (unsigned)(size_t)(__attribute__((address_space(3))) ushort_t*)&lds[0][0][0];
  const int x7 = q15 & 7;
  const unsigned laneA = (unsigned)(q15 * 128);
  const unsigned c0 = (unsigned)((g ^ x7) * 16);
  const unsigned c1 = (unsigned)(((4 | g) ^ x7) * 16);
  const unsigned aAk0b0 = lbase + wm * 8192 + laneA + c0;
  const unsigned aAk1b0 = lbase + wm * 8192 + laneA + c1;
  const unsigned aAk0b1 = aAk0b0 + 65536;
  const unsigned aAk1b1 = aAk1b0 + 65536;
  const unsigned aBk0b0 = lbase + 32768 + wn * 8192 + laneA + c0;
  const unsigned aBk1b0 = lbase + 32768 + wn * 8192 + laneA + c1;
  const unsigned aBk0b1 = aBk0b0 + 65536;
  const unsigned aBk1b1 = aBk1b0 + 65536;

#define AOFFC(M) (((M) & 4) * 4096 + ((M) & 3) * 2048)
#define RDA(BUF, M0, M1) do{                                             \
    af[0][0] = dsr<AOFFC(M0)>(aAk0b##BUF);                               \
    af[0][1] = dsr<AOFFC(M0)>(aAk1b##BUF);                               \
    af[1][0] = dsr<AOFFC(M1)>(aAk0b##BUF);                               \
    af[1][1] = dsr<AOFFC(M1)>(aAk1b##BUF); }while(0)
#define RDB(BUF) do{                                                     \
    bf[0][0] = dsr<0>(aBk0b##BUF);    bf[0][1] = dsr<0>(aBk1b##BUF);     \
    bf[1][0] = dsr<2048>(aBk0b##BUF); bf[1][1] = dsr<2048>(aBk1b##BUF);  \
    bf[2][0] = dsr<4096>(aBk0b##BUF); bf[2][1] = dsr<4096>(aBk1b##BUF);  \
    bf[3][0] = dsr<6144>(aBk0b##BUF); bf[3][1] = dsr<6144>(aBk1b##BUF); }while(0)

#define LGK0 do{ asm volatile("s_waitcnt lgkmcnt(0)");                   \
                 __builtin_amdgcn_sched_barrier(0); }while(0)

#define CLUSTER(R0, R1) do{                                              \
    __builtin_amdgcn_s_setprio(1);                                       \
    MFMA16A(acc[R0][0], af[0][0], bf[0][0]);                             \
    MFMA16A(acc[R0][1], af[0][0], bf[1][0]);                             \
    MFMA16A(acc[R0][2], af[0][0], bf[2][0]);                             \
    MFMA16A(acc[R0][3], af[0][0], bf[3][0]);                             \
    MFMA16A(acc[R1][0], af[1][0], bf[0][0]);                             \
    MFMA16A(acc[R1][1], af[1][0], bf[1][0]);                             \
    MFMA16A(acc[R1][2], af[1][0], bf[2][0]);                             \
    MFMA16A(acc[R1][3], af[1][0], bf[3][0]);                             \
    MFMA16A(acc[R0][0], af[0][1], bf[0][1]);                             \
    MFMA16A(acc[R0][1], af[0][1], bf[1][1]);                             \
    MFMA16A(acc[R0][2], af[0][1], bf[2][1]);                             \
    MFMA16A(acc[R0][3], af[0][1], bf[3][1]);                             \
    MFMA16A(acc[R1][0], af[1][1], bf[0][1]);                             \
    MFMA16A(acc[R1][1], af[1][1], bf[1][1]);                             \
    MFMA16A(acc[R1][2], af[1][1], bf[2][1]);                             \
    MFMA16A(acc[R1][3], af[1][1], bf[3][1]);                             \
    __builtin_amdgcn_s_setprio(0); }while(0)

#define HALF(BUF, OBUF, ktA23, PFA, ktN, PFN, W1C, W3C)                  \
  do {                                                                   \
    if (PFA) { SA(OBUF, 2, ktA23); SA(OBUF, 3, ktA23); }                 \
    RDB(BUF); RDA(BUF, 0, 1);                                            \
    __builtin_amdgcn_s_barrier();                                        \
    LGK0; CLUSTER(0, 1);                                                 \
    __builtin_amdgcn_s_barrier();                                        \
    if (PFN) { SB(BUF, 0, ktN); SB(BUF, 1, ktN); }                       \
    RDA(BUF, 2, 3);                                                      \
    __builtin_amdgcn_s_barrier();                                        \
    LGK0; CLUSTER(2, 3);                                                 \
    W1C;                                                                 \
    __builtin_amdgcn_s_barrier();                                        \
    if (PFN) { SB(BUF, 2, ktN); SB(BUF, 3, ktN); }                       \
    RDA(BUF, 4, 5);                                                      \
    __builtin_amdgcn_s_barrier();                                        \
    LGK0; CLUSTER(4, 5);                                                 \
    __builtin_amdgcn_s_barrier();                                        \
    if (PFN) { SA(BUF, 0, ktN); SA(BUF, 1, ktN); }                       \
    RDA(BUF, 6, 7);                                                      \
    __builtin_amdgcn_s_barrier();                                        \
    LGK0; CLUSTER(6, 7);                                                 \
    W3C;                                                                 \
    __builtin_amdgcn_s_barrier();                                        \
  } while (0)

  f32x4 acc[8][4];
#pragma unroll
  for (int a = 0; a < 8; ++a)
#pragma unroll
    for (int b = 0; b < 4; ++b) acc[a][b] = (f32x4)0.0f;

  u32x4 bf[4][2], af[2][2];

  // prologue (nkt >= 4): tile0 fully + tile1's B + A01 = 14 loads
  SB(0, 0, 0); SB(0, 1, 0); SB(0, 2, 0); SB(0, 3, 0);
  SA(0, 0, 0); SA(0, 1, 0); SA(0, 2, 0); SA(0, 3, 0);
  SB(1, 0, 1); SB(1, 1, 1); SB(1, 2, 1); SB(1, 3, 1);
  SA(1, 0, 1); SA(1, 1, 1);
  VM(8);                                   // certify B(0)+A01(0)
  __builtin_amdgcn_s_barrier();

  int kt = 0;
  for (; kt + 3 < nkt; kt += 2) {
    HALF(0, 1, kt + 1, true, kt + 2, true, VM(10), VM(8));
    HALF(1, 0, kt + 2, true, kt + 3, true, VM(10), VM(8));
  }
  // tail: tiles nkt-2 (buf0) and nkt-1 (buf1), no further prefetch
  HALF(0, 1, kt + 1, true,  kt + 2, false, VM(8), VM(2));
  HALF(1, 0, kt + 2, false, kt + 3, false, VM(0), NOOP);

  // epilogue (rows: (m&4)*32 + wm*64 + (m&3)*16 + g*4 + i)
#pragma unroll
  for (int m = 0; m < 8; ++m) {
    const int row0 = bm + ((m & 4) << 5) + (wm << 6) + ((m & 3) << 4) + (g << 2);
#pragma unroll
    for (int n = 0; n < 4; ++n) {
      const int col = bn + (wn << 6) + (n << 4) + q15;
      float bv = 0.0f;
      if constexpr (EPI != 4) bv = bias[col];
#pragma unroll
      for (int i = 0; i < 4; ++i) {
        const int mrow = row0 + i;
        float v = acc[m][n][i] + bv;
        if constexpr (EPI == 0) {
          const int sel = col >> 11, hd = col & 2047, h = hd >> 6, d = hd & 63;
          const int b = mrow >> 11, t = mrow & 2047;
          if (sel == 0) {
            // fold 1/sqrt(64) * log2(e) into Q (softmax runs in exp2 domain)
            ((__hip_bfloat16*)o0)[((size_t)(b * NH + h) * TT + t) * HD + d] =
                __float2bfloat16(v * 0.18033688011112042f);
          } else if (sel == 1) {
            ((__hip_bfloat16*)o1)[((size_t)(b * NH + h) * TT + t) * HD + d] =
                __float2bfloat16(v);
          } else {
            ((__hip_bfloat16*)o2)[((size_t)(b * NH + h) * HD + d) * TT + t] =
                __float2bfloat16(v);  // V transposed: [B,H,D,T]
          }
        } else if constexpr (EPI == 2) {
          ((__hip_bfloat16*)o0)[(size_t)mrow * N + col] =
              __float2bfloat16(0.5f * v * (1.0f + erff(v * 0.70710678118654752f)));
        } else {  // EPI == 4: raw split-K partial
          ((float*)(blockIdx.y ? o1 : o0))[(size_t)mrow * N + col] = v;
        }
      }
    }
  }
#undef SA
#undef SB
#undef RDA
#undef RDB
#undef HALF
#undef CLUSTER
#undef LGK0
#undef AOFFC
}

// ---------------------------------------------------------------------------
// split-K combine: out = p0 + p1 + bias + res (fp32, float4)
// ---------------------------------------------------------------------------
__global__ __launch_bounds__(256)
void combine2(const float* __restrict__ p0, const float* __restrict__ p1,
              const float* __restrict__ bias, const float* __restrict__ res,
              float* __restrict__ out) {
  const size_t i = ((size_t)blockIdx.x * 256 + threadIdx.x) << 2;
  const float4 a = *(const float4*)(p0 + i);
  const float4 b = *(const float4*)(p1 + i);
  const float4 r = *(const float4*)(res + i);
  const float4 bi = *(const float4*)(bias + (i & (DIM - 1)));
  float4 o;
  o.x = a.x + b.x + r.x + bi.x;
  o.y = a.y + b.y + r.y + bi.y;
  o.z = a.z + b.z + r.z + bi.z;
  o.w = a.w + b.w + r.w + bi.w;
  *(float4*)(out + i) = o;
}

// ---------------------------------------------------------------------------
// 128x128-tile GEMM (m97 structure, 2D x-fast grid, no swizzle — the R1/R6
// proven form).  Kept for the small O-proj GEMM.  EPI 1: + res -> fp32 out
// ---------------------------------------------------------------------------
template <int EPI>
__global__ __launch_bounds__(256)
void gemm_bt(const __hip_bfloat16* __restrict__ A, const __hip_bfloat16* __restrict__ Bt,
             const float* __restrict__ bias, const float* __restrict__ res,
             void* __restrict__ o0, int M, int N, int K) {
  __shared__ __hip_bfloat16 As[128 * 32];
  __shared__ __hip_bfloat16 Bs[128 * 32];
  const int tid = threadIdx.x;
  const int l = tid & 63, w = tid >> 6;
  const int wr = w >> 1, wc = w & 1;
  const int g = l >> 4, q15 = l & 15;
  const int bm = blockIdx.y * 128, bn = blockIdx.x * 128;

  f32x4 acc[4][4];
#pragma unroll
  for (int a = 0; a < 4; ++a)
#pragma unroll
    for (int b = 0; b < 4; ++b) acc[a][b] = (f32x4)0.0f;

  const __hip_bfloat16* aSrc = A  + (size_t)(bm + (tid >> 2)) * K + (tid & 3) * 8;
  const __hip_bfloat16* bSrc = Bt + (size_t)(bn + (tid >> 2)) * K + (tid & 3) * 8;
  __hip_bfloat16* aDst = As + tid * 8;
  __hip_bfloat16* bDst = Bs + tid * 8;
  const size_t rowStep = (size_t)64 * K;

  for (int kt = 0; kt < K; kt += 32) {
    GL16(aSrc + kt,            aDst);
    GL16(aSrc + rowStep + kt,  aDst + 2048);
    GL16(bSrc + kt,            bDst);
    GL16(bSrc + rowStep + kt,  bDst + 2048);
    __syncthreads();
    u32x4 af[4], bf[4];
#pragma unroll
    for (int rb = 0; rb < 4; ++rb)
      af[rb] = *(const u32x4*)(As + (wr * 64 + rb * 16 + q15) * 32 + g * 8);
#pragma unroll
    for (int cb = 0; cb < 4; ++cb)
      bf[cb] = *(const u32x4*)(Bs + (wc * 64 + cb * 16 + q15) * 32 + g * 8);
#pragma unroll
    for (int rb = 0; rb < 4; ++rb)
#pragma unroll
      for (int cb = 0; cb < 4; ++cb) MFMA16(acc[rb][cb], af[rb], bf[cb]);
    __syncthreads();
  }

#pragma unroll
  for (int rb = 0; rb < 4; ++rb) {
    const int row0 = bm + wr * 64 + rb * 16 + g * 4;
#pragma unroll
    for (int cb = 0; cb < 4; ++cb) {
      const int col = bn + wc * 64 + cb * 16 + q15;
      const float bv = bias[col];
#pragma unroll
      for (int i = 0; i < 4; ++i) {
        const int m = row0 + i;
        float v = acc[rb][cb][i] + bv;
        ((float*)o0)[(size_t)m * N + col] = v + res[(size_t)m * N + col];
      }
    }
  }
}

// ---------------------------------------------------------------------------
// Flash attention.  VALU-trimmed softmax: exp2-domain scores (log2e folded
// into Q), v_cvt_pk_bf16_f32 packing, defer-max (THR=8, log2 units), v_max3
// row-max tree, K-tile register prefetch, setprio around MFMA clusters.
// ---------------------------------------------------------------------------
__global__ __launch_bounds__(256)
void attn_kernel(const __hip_bfloat16* __restrict__ Q, const __hip_bfloat16* __restrict__ Kx,
                 const __hip_bfloat16* __restrict__ Vt, __hip_bfloat16* __restrict__ out) {
  __shared__ unsigned int Plds[4][2048];  // 8KB per wave
  const int tid = threadIdx.x;
  const int l = tid & 63, w = tid >> 6;
  const int g = l >> 4, q15 = l & 15;
  const int bh = blockIdx.x >> 3;
  const int q0 = (blockIdx.x & 7) * 256 + w * 64;
  const __hip_bfloat16* Qb = Q  + (size_t)bh * TT * HD;
  const __hip_bfloat16* Kb = Kx + (size_t)bh * TT * HD;
  const __hip_bfloat16* Vb = Vt + (size_t)bh * HD * TT;
  unsigned int* Pw = Plds[w];

  u32x4 qf[4][2];
#pragma unroll
  for (int rb = 0; rb < 4; ++rb)
#pragma unroll
    for (int ks = 0; ks < 2; ++ks)
      qf[rb][ks] = *(const u32x4*)(Qb + (size_t)(q0 + rb * 16 + q15) * HD + ks * 32 + g * 8);

  f32x4 acc[4][4];  // [db][rb]
#pragma unroll
  for (int a = 0; a < 4; ++a)
#pragma unroll
    for (int b = 0; b < 4; ++b) acc[a][b] = (f32x4)0.0f;
  float mstat[4] = {-3e38f, -3e38f, -3e38f, -3e38f};
  float lstat[4] = {0.f, 0.f, 0.f, 0.f};

  u32x4 kf[2][4];
#pragma unroll
  for (int cb = 0; cb < 4; ++cb)
#pragma unroll
    for (int ks = 0; ks < 2; ++ks)
      kf[ks][cb] = *(const u32x4*)(Kb + (size_t)(cb * 16 + q15) * HD + ks * 32 + g * 8);

  for (int s0 = 0; s0 < TT; s0 += 64) {
    f32x4 st[4][4];  // [cb][rb] = S^T (exp2-domain logits)
#pragma unroll
    for (int a = 0; a < 4; ++a)
#pragma unroll
      for (int b = 0; b < 4; ++b) st[a][b] = (f32x4)0.0f;
    __builtin_amdgcn_s_setprio(1);
#pragma unroll
    for (int ks = 0; ks < 2; ++ks)
#pragma unroll
      for (int cb = 0; cb < 4; ++cb)
#pragma unroll
        for (int rb = 0; rb < 4; ++rb) MFMA16(st[cb][rb], kf[ks][cb], qf[rb][ks]);
    __builtin_amdgcn_s_setprio(0);
    // prefetch next K tile (kf dead after QK^T) — hides under softmax+PV
    if (s0 + 64 < TT) {
#pragma unroll
      for (int cb = 0; cb < 4; ++cb)
#pragma unroll
        for (int ks = 0; ks < 2; ++ks)
          kf[ks][cb] = *(const u32x4*)(Kb + (size_t)(s0 + 64 + cb * 16 + q15) * HD + ks * 32 + g * 8);
    }
#pragma unroll
    for (int rb = 0; rb < 4; ++rb) {
      // row-max tree (v_max3)
      float a0 = fmax3(st[0][rb][0], st[0][rb][1], st[0][rb][2]);
      float a1 = fmax3(st[0][rb][3], st[1][rb][0], st[1][rb][1]);
      float a2 = fmax3(st[1][rb][2], st[1][rb][3], st[2][rb][0]);
      float a3 = fmax3(st[2][rb][1], st[2][rb][2], st[2][rb][3]);
      float a4 = fmax3(st[3][rb][0], st[3][rb][1], st[3][rb][2]);
      float pm = fmax3(fmax3(a0, a1, a2), a3, fmax3(a4, st[3][rb][3], a0));
      pm = fmaxf(pm, __shfl_xor(pm, 16));
      pm = fmaxf(pm, __shfl_xor(pm, 32));
      // defer-max: only rescale when the running max grows by > 8 (log2)
      if (!__all(pm <= mstat[rb] + 8.0f)) {
        const float mnew = fmaxf(mstat[rb], pm);
        const float corr = fexp2(mstat[rb] - mnew);
        mstat[rb] = mnew;
        lstat[rb] *= corr;
#pragma unroll
        for (int db = 0; db < 4; ++db)
#pragma unroll
          for (int i = 0; i < 4; ++i) acc[db][rb][i] *= corr;
      }
      const float mcur = mstat[rb];
      float rs = 0.f;
      const int row = rb * 16 + q15;
      const int rx = row & 7;
#pragma unroll
      for (int cb = 0; cb < 4; ++cb) {
        const float p0 = fexp2(st[cb][rb][0] - mcur);
        const float p1 = fexp2(st[cb][rb][1] - mcur);
        const float p2 = fexp2(st[cb][rb][2] - mcur);
        const float p3 = fexp2(st[cb][rb][3] - mcur);
        rs += (p0 + p1) + (p2 + p3);
        const int seg = (cb * 2 + (g >> 1)) ^ rx;
        u32x2 pk = {cvtpk(p0, p1), cvtpk(p2, p3)};
        *(u32x2*)(Pw + row * 32 + seg * 4 + (g & 1) * 2) = pk;
      }
      rs += __shfl_xor(rs, 16);
      rs += __shfl_xor(rs, 32);
      lstat[rb] += rs;
    }
    // V loads batched (independent of P write settling)
    u32x4 vf[2][4];
#pragma unroll
    for (int ks2 = 0; ks2 < 2; ++ks2)
#pragma unroll
      for (int db = 0; db < 4; ++db)
        vf[ks2][db] = *(const u32x4*)(Vb + (size_t)(db * 16 + q15) * TT + s0 + ks2 * 32 + g * 8);
    u32x4 pf[2][4];
#pragma unroll
    for (int ks2 = 0; ks2 < 2; ++ks2)
#pragma unroll
      for (int rb = 0; rb < 4; ++rb) {
        const int row = rb * 16 + q15;
        const int seg = (ks2 * 4 + g) ^ (row & 7);
        pf[ks2][rb] = *(const u32x4*)(Pw + row * 32 + seg * 4);
      }
    __builtin_amdgcn_s_setprio(1);
#pragma unroll
    for (int ks2 = 0; ks2 < 2; ++ks2)
#pragma unroll
      for (int db = 0; db < 4; ++db)
#pragma unroll
        for (int rb = 0; rb < 4; ++rb) MFMA16(acc[db][rb], vf[ks2][db], pf[ks2][rb]);
    __builtin_amdgcn_s_setprio(0);
  }
  const int b = bh >> 5, hh = bh & 31;
#pragma unroll
  for (int rb = 0; rb < 4; ++rb) {
    const float inv = 1.0f / lstat[rb];
    const size_t trow = (size_t)(b * TT + q0 + rb * 16 + q15);
#pragma unroll
    for (int db = 0; db < 4; ++db) {
      u32x2 pk = {cvtpk(acc[db][rb][0] * inv, acc[db][rb][1] * inv),
                  cvtpk(acc[db][rb][2] * inv, acc[db][rb][3] * inv)};
      *(u32x2*)(out + trow * DIM + hh * 64 + db * 16 + g * 4) = pk;
    }
  }
}

// ---------------------------------------------------------------------------
extern "C" void kernel_launch(void* const* d_in, const int* in_sizes, int n_in,
                              void* d_out, int out_size, void* d_ws, size_t ws_size,
                              hipStream_t stream) {
  (void)in_sizes; (void)n_in; (void)out_size; (void)ws_size;
  const float* x     = (const float*)d_in[0];
  const float* w_qkv = (const float*)d_in[1];
  const float* b_qkv = (const float*)d_in[2];
  const float* w_o   = (const float*)d_in[3];
  const float* b_o   = (const float*)d_in[4];
  const float* g1    = (const float*)d_in[5];
  const float* be1   = (const float*)d_in[6];
  const float* w1    = (const float*)d_in[7];
  const float* b1    = (const float*)d_in[8];
  const float* w2    = (const float*)d_in[9];
  const float* b2    = (const float*)d_in[10];
  const float* g2    = (const float*)d_in[11];
  const float* be2   = (const float*)d_in[12];

  char* ws = (char*)d_ws;
  size_t off = 0;
  auto alloc = [&](size_t bytes) {
    void* p = ws + off;
    off += (bytes + 255) & ~(size_t)255;
    return p;
  };
  __hip_bfloat16* WqkvT = (__hip_bfloat16*)alloc((size_t)6144 * 2048 * 2);  // 24MB
  __hip_bfloat16* WoT   = (__hip_bfloat16*)alloc((size_t)2048 * 2048 * 2);  //  8MB
  __hip_bfloat16* W1T   = (__hip_bfloat16*)alloc((size_t)8192 * 2048 * 2);  // 32MB
  __hip_bfloat16* W2T   = (__hip_bfloat16*)alloc((size_t)2048 * 8192 * 2);  // 32MB
  __hip_bfloat16* hbuf  = (__hip_bfloat16*)alloc((size_t)MM * DIM * 2);
  float*          xres  = (float*)alloc((size_t)MM * DIM * 4);
  __hip_bfloat16* Qb    = (__hip_bfloat16*)alloc((size_t)MM * DIM * 2);
  __hip_bfloat16* Kb    = (__hip_bfloat16*)alloc((size_t)MM * DIM * 2);
  __hip_bfloat16* Vtb   = (__hip_bfloat16*)alloc((size_t)MM * DIM * 2);
  __hip_bfloat16* attno = (__hip_bfloat16*)alloc((size_t)MM * DIM * 2);
  __hip_bfloat16* f1    = Qb;  // FFN hidden aliases Q/K/Vt/attno (dead then)
  // split-K partials alias WqkvT+WoT (p0) and W1T (p1) — all dead by FFN2
  float* p0 = (float*)ws;
  float* p1 = (float*)(ws + (size_t)MM * DIM * 4);

  const dim3 tb(32, 8);
  transpose_cvt<<<dim3(6144 / 32, 2048 / 32), tb, 0, stream>>>(w_qkv, WqkvT, 2048, 6144);
  transpose_cvt<<<dim3(2048 / 32, 2048 / 32), tb, 0, stream>>>(w_o, WoT, 2048, 2048);
  transpose_cvt<<<dim3(8192 / 32, 2048 / 32), tb, 0, stream>>>(w1, W1T, 2048, 8192);
  transpose_cvt<<<dim3(2048 / 32, 8192 / 32), tb, 0, stream>>>(w2, W2T, 8192, 2048);

  ln_kernel<<<MM, 256, 0, stream>>>(x, g1, be1, hbuf);
  gemm256<0><<<dim3((6144 / 256) * (MM / 256)), 512, 0, stream>>>(
      hbuf, WqkvT, b_qkv, nullptr, Qb, Kb, Vtb, MM, 6144, 2048, 32);
  attn_kernel<<<512, 256, 0, stream>>>(Qb, Kb, Vtb, attno);
  gemm_bt<1><<<dim3(2048 / 128, MM / 128), 256, 0, stream>>>(
      attno, WoT, b_o, x, xres, MM, 2048, 2048);
  ln_kernel<<<MM, 256, 0, stream>>>(xres, g2, be2, hbuf);
  gemm256<2><<<dim3((8192 / 256) * (MM / 256)), 512, 0, stream>>>(
      hbuf, W1T, b1, nullptr, f1, nullptr, nullptr, MM, 8192, 2048, 32);
  gemm256<4><<<dim3((2048 / 256) * (MM / 256), 2), 512, 0, stream>>>(
      f1, W2T, nullptr, nullptr, p0, p1, nullptr, MM, 2048, 8192, 64);
  combine2<<<(MM * DIM) / 1024, 256, 0, stream>>>(p0, p1, b2, xres, (float*)d_out);
}

// Round 9
// 698.690 us; speedup vs baseline: 1.2095x; 1.0259x over previous
//
#include <hip/hip_runtime.h>
#include <hip/hip_bf16.h>

#define DIM  2048
#define DFF  8192
#define NH   32
#define HD   64
#define TT   2048
#define MM   4096   // B*T

typedef __attribute__((ext_vector_type(4))) float f32x4;
typedef __attribute__((ext_vector_type(4))) unsigned int u32x4;
typedef __attribute__((ext_vector_type(2))) unsigned int u32x2;
typedef unsigned short ushort_t;

// D = A*B + D, bf16 16x16x32 (VGPR acc)
#define MFMA16(ACC, A, B) \
  asm volatile("v_mfma_f32_16x16x32_bf16 %0, %1, %2, %0" : "+v"(ACC) : "v"(A), "v"(B))
// AGPR-accumulator variant (gemm256: keeps 128-float acc pinned in AGPRs)
#define MFMA16A(ACC, A, B) \
  asm volatile("v_mfma_f32_16x16x32_bf16 %0, %1, %2, %0" : "+a"(ACC) : "v"(A), "v"(B))

// async global->LDS, 16B per lane (dest = wave-uniform base + lane*16)
#define GL16(GP, LP)                                                     \
  __builtin_amdgcn_global_load_lds(                                      \
      (const __attribute__((address_space(1))) void*)(GP),               \
      (__attribute__((address_space(3))) void*)(LP), 16, 0, 0)

// Hand waitcnt WITHOUT a "memory" clobber; placement pinned by sched_barrier.
#define VM(N) do{ asm volatile("s_waitcnt vmcnt(" #N ")");               \
                  __builtin_amdgcn_sched_barrier(0); }while(0)
#define NOOP  ((void)0)

// opaque ds_read_b128 (invisible to SIInsertWaitcnts' LDS-DMA alias check)
template <int IMM>
__device__ __forceinline__ u32x4 dsr(unsigned a) {
  u32x4 d;
  asm volatile("ds_read_b128 %0, %1 offset:%2" : "=v"(d) : "v"(a), "i"(IMM));
  return d;
}

__device__ __forceinline__ unsigned int f2bu(float f) {
  union { __hip_bfloat16 h; unsigned short u; } c;
  c.h = __float2bfloat16(f);
  return (unsigned int)c.u;
}
// 2^x via native transcendental
__device__ __forceinline__ float fexp2(float x) {
  float r; asm("v_exp_f32 %0, %1" : "=v"(r) : "v"(x)); return r;
}
// pack two f32 -> bf16x2 in one instr (no builtin on gfx950)
__device__ __forceinline__ unsigned cvtpk(float lo, float hi) {
  unsigned r; asm("v_cvt_pk_bf16_f32 %0, %1, %2" : "=v"(r) : "v"(lo), "v"(hi));
  return r;
}
__device__ __forceinline__ float fmax3(float a, float b, float c) {
  float r; asm("v_max3_f32 %0, %1, %2, %3" : "=v"(r) : "v"(a), "v"(b), "v"(c));
  return r;
}

// ---------------------------------------------------------------------------
// Transpose + fp32->bf16 convert: in[R,C] fp32 -> out[C,R] bf16
// ---------------------------------------------------------------------------
__global__ __launch_bounds__(256)
void transpose_cvt(const float* __restrict__ in, __hip_bfloat16* __restrict__ out,
                   int R, int C) {
  __shared__ float tile[32][33];
  const int tx = threadIdx.x, ty = threadIdx.y;       // (32, 8)
  const int bx = blockIdx.x * 32, by = blockIdx.y * 32;
#pragma unroll
  for (int i = 0; i < 32; i += 8)
    tile[ty + i][tx] = in[(size_t)(by + ty + i) * C + bx + tx];
  __syncthreads();
#pragma unroll
  for (int i = 0; i < 32; i += 8)
    out[(size_t)(bx + ty + i) * R + by + tx] = __float2bfloat16(tile[tx][ty + i]);
}

// ---------------------------------------------------------------------------
// LayerNorm: fp32 [rows, 2048] -> bf16, one block (256 thr) per row
// ---------------------------------------------------------------------------
__global__ __launch_bounds__(256)
void ln_kernel(const float* __restrict__ in, const float* __restrict__ gw,
               const float* __restrict__ bw, __hip_bfloat16* __restrict__ out) {
  const int row = blockIdx.x;
  const int t = threadIdx.x;
  const float* x = in + (size_t)row * DIM;
  const float4 v0 = ((const float4*)x)[t * 2];
  const float4 v1 = ((const float4*)x)[t * 2 + 1];
  float s  = v0.x + v0.y + v0.z + v0.w + v1.x + v1.y + v1.z + v1.w;
  float ss = v0.x*v0.x + v0.y*v0.y + v0.z*v0.z + v0.w*v0.w
           + v1.x*v1.x + v1.y*v1.y + v1.z*v1.z + v1.w*v1.w;
#pragma unroll
  for (int o = 32; o >= 1; o >>= 1) { s += __shfl_xor(s, o); ss += __shfl_xor(ss, o); }
  __shared__ float red[8];
  if ((t & 63) == 0) { red[t >> 6] = s; red[4 + (t >> 6)] = ss; }
  __syncthreads();
  s  = red[0] + red[1] + red[2] + red[3];
  ss = red[4] + red[5] + red[6] + red[7];
  const float mean = s * (1.0f / DIM);
  const float rstd = rsqrtf(ss * (1.0f / DIM) - mean * mean + 1e-5f);
  const float4 g0 = ((const float4*)gw)[t * 2], g1 = ((const float4*)gw)[t * 2 + 1];
  const float4 b0 = ((const float4*)bw)[t * 2], b1 = ((const float4*)bw)[t * 2 + 1];
  uint4 o;
  o.x = f2bu((v0.x - mean) * rstd * g0.x + b0.x) | (f2bu((v0.y - mean) * rstd * g0.y + b0.y) << 16);
  o.y = f2bu((v0.z - mean) * rstd * g0.z + b0.z) | (f2bu((v0.w - mean) * rstd * g0.w + b0.w) << 16);
  o.z = f2bu((v1.x - mean) * rstd * g1.x + b1.x) | (f2bu((v1.y - mean) * rstd * g1.y + b1.y) << 16);
  o.w = f2bu((v1.z - mean) * rstd * g1.z + b1.z) | (f2bu((v1.w - mean) * rstd * g1.w + b1.w) << 16);
  *(uint4*)((char*)out + ((size_t)row * DIM + t * 8) * 2) = o;
}

// ---------------------------------------------------------------------------
// 256x256 tile, BK=64, 8 waves, deep-pipelined 4-phase/K-tile (R6 form).
// EPI 2: gelu->bf16 (FFN1); EPI 4: split-K bf16 partial (FFN2)
// ---------------------------------------------------------------------------
template <int EPI>
__global__ __launch_bounds__(512, 2)
void gemm256(const __hip_bfloat16* __restrict__ Abf, const __hip_bfloat16* __restrict__ Btbf,
             const float* __restrict__ bias, const float* __restrict__ res,
             void* __restrict__ o0, void* __restrict__ o1, void* __restrict__ o2,
             int M, int N, int K, int nkt) {
  __shared__ ushort_t lds[2][2][16384];   // [dbuf][A=0/B=1][256*64] = 128 KiB
  const int tid = threadIdx.x;
  const int l = tid & 63, w = tid >> 6;
  const int wm = w >> 2, wn = w & 3;
  const int g = l >> 4, q15 = l & 15;

  const int nby = M >> 8;
  const int nwg = (N >> 8) * nby;
  int id = blockIdx.x;
  { // bijective XCD swizzle (m204)
    const int qq = nwg >> 3, rr = nwg & 7;
    const int xcd = id & 7, pos = id >> 3;
    id = (xcd < rr ? xcd * (qq + 1) : rr * (qq + 1) + (xcd - rr) * qq) + pos;
  }
  const int bm = (id % nby) << 8;
  const int bn = (id / nby) << 8;
  const int k0 = (EPI == 4) ? (int)blockIdx.y * (nkt << 6) : 0;

  // staging: linear LDS dest + inverse-swizzled global source (rule #21)
  const ushort_t* Au = (const ushort_t*)Abf;
  const ushort_t* Bu = (const ushort_t*)Btbf;
  const int sr = tid >> 3;                         // row within 64-row group
  const int sc = (((tid & 7) ^ (sr & 7)) << 3);    // swizzled col (elements)
  const ushort_t* aBase = Au + (size_t)(bm + sr) * K + (k0 + sc);
  const ushort_t* bBase = Bu + (size_t)(bn + sr) * K + (k0 + sc);
  const int dOff = (w << 9) + (l << 3);            // element off within group

#define SA(BUF, GRP, KT_)                                                \
  GL16(aBase + (size_t)((GRP) << 6) * K + ((KT_) << 6),                  \
       &lds[BUF][0][((GRP) << 12) + dOff])
#define SB(BUF, GRP, KT_)                                                \
  GL16(bBase + (size_t)((GRP) << 6) * K + ((KT_) << 6),                  \
       &lds[BUF][1][((GRP) << 12) + dOff])

  const unsigned lbase =
      (unsigned)(size_t)(__attribute__((address_space(3))) ushort_t*)&lds[0][0][0];
  const int x7 = q15 & 7;
  const unsigned laneA = (unsigned)(q15 * 128);
  const unsigned c0 = (unsigned)((g ^ x7) * 16);
  const unsigned c1 = (unsigned)(((4 | g) ^ x7) * 16);
  const unsigned aAk0b0 = lbase + wm * 8192 + laneA + c0;
  const unsigned aAk1b0 = lbase + wm * 8192 + laneA + c1;
  const unsigned aAk0b1 = aAk0b0 + 65536;
  const unsigned aAk1b1 = aAk1b0 + 65536;
  const unsigned aBk0b0 = lbase + 32768 + wn * 8192 + laneA + c0;
  const unsigned aBk1b0 = lbase + 32768 + wn * 8192 + laneA + c1;
  const unsigned aBk0b1 = aBk0b0 + 65536;
  const unsigned aBk1b1 = aBk1b0 + 65536;

#define AOFFC(M) (((M) & 4) * 4096 + ((M) & 3) * 2048)
#define RDA(BUF, M0, M1) do{                                             \
    af[0][0] = dsr<AOFFC(M0)>(aAk0b##BUF);                               \
    af[0][1] = dsr<AOFFC(M0)>(aAk1b##BUF);                               \
    af[1][0] = dsr<AOFFC(M1)>(aAk0b##BUF);                               \
    af[1][1] = dsr<AOFFC(M1)>(aAk1b##BUF); }while(0)
#define RDB(BUF) do{                                                     \
    bf[0][0] = dsr<0>(aBk0b##BUF);    bf[0][1] = dsr<0>(aBk1b##BUF);     \
    bf[1][0] = dsr<2048>(aBk0b##BUF); bf[1][1] = dsr<2048>(aBk1b##BUF);  \
    bf[2][0] = dsr<4096>(aBk0b##BUF); bf[2][1] = dsr<4096>(aBk1b##BUF);  \
    bf[3][0] = dsr<6144>(aBk0b##BUF); bf[3][1] = dsr<6144>(aBk1b##BUF); }while(0)

#define LGK0 do{ asm volatile("s_waitcnt lgkmcnt(0)");                   \
                 __builtin_amdgcn_sched_barrier(0); }while(0)

#define CLUSTER(R0, R1) do{                                              \
    __builtin_amdgcn_s_setprio(1);                                       \
    MFMA16A(acc[R0][0], af[0][0], bf[0][0]);                             \
    MFMA16A(acc[R0][1], af[0][0], bf[1][0]);                             \
    MFMA16A(acc[R0][2], af[0][0], bf[2][0]);                             \
    MFMA16A(acc[R0][3], af[0][0], bf[3][0]);                             \
    MFMA16A(acc[R1][0], af[1][0], bf[0][0]);                             \
    MFMA16A(acc[R1][1], af[1][0], bf[1][0]);                             \
    MFMA16A(acc[R1][2], af[1][0], bf[2][0]);                             \
    MFMA16A(acc[R1][3], af[1][0], bf[3][0]);                             \
    MFMA16A(acc[R0][0], af[0][1], bf[0][1]);                             \
    MFMA16A(acc[R0][1], af[0][1], bf[1][1]);                             \
    MFMA16A(acc[R0][2], af[0][1], bf[2][1]);                             \
    MFMA16A(acc[R0][3], af[0][1], bf[3][1]);                             \
    MFMA16A(acc[R1][0], af[1][1], bf[0][1]);                             \
    MFMA16A(acc[R1][1], af[1][1], bf[1][1]);                             \
    MFMA16A(acc[R1][2], af[1][1], bf[2][1]);                             \
    MFMA16A(acc[R1][3], af[1][1], bf[3][1]);                             \
    __builtin_amdgcn_s_setprio(0); }while(0)

#define HALF(BUF, OBUF, ktA23, PFA, ktN, PFN, W1C, W3C)                  \
  do {                                                                   \
    if (PFA) { SA(OBUF, 2, ktA23); SA(OBUF, 3, ktA23); }                 \
    RDB(BUF); RDA(BUF, 0, 1);                                            \
    __builtin_amdgcn_s_barrier();                                        \
    LGK0; CLUSTER(0, 1);                                                 \
    __builtin_amdgcn_s_barrier();                                        \
    if (PFN) { SB(BUF, 0, ktN); SB(BUF, 1, ktN); }                       \
    RDA(BUF, 2, 3);                                                      \
    __builtin_amdgcn_s_barrier();                                        \
    LGK0; CLUSTER(2, 3);                                                 \
    W1C;                                                                 \
    __builtin_amdgcn_s_barrier();                                        \
    if (PFN) { SB(BUF, 2, ktN); SB(BUF, 3, ktN); }                       \
    RDA(BUF, 4, 5);                                                      \
    __builtin_amdgcn_s_barrier();                                        \
    LGK0; CLUSTER(4, 5);                                                 \
    __builtin_amdgcn_s_barrier();                                        \
    if (PFN) { SA(BUF, 0, ktN); SA(BUF, 1, ktN); }                       \
    RDA(BUF, 6, 7);                                                      \
    __builtin_amdgcn_s_barrier();                                        \
    LGK0; CLUSTER(6, 7);                                                 \
    W3C;                                                                 \
    __builtin_amdgcn_s_barrier();                                        \
  } while (0)

  f32x4 acc[8][4];
#pragma unroll
  for (int a = 0; a < 8; ++a)
#pragma unroll
    for (int b = 0; b < 4; ++b) acc[a][b] = (f32x4)0.0f;

  u32x4 bf[4][2], af[2][2];

  // prologue (nkt >= 4): tile0 fully + tile1's B + A01 = 14 loads
  SB(0, 0, 0); SB(0, 1, 0); SB(0, 2, 0); SB(0, 3, 0);
  SA(0, 0, 0); SA(0, 1, 0); SA(0, 2, 0); SA(0, 3, 0);
  SB(1, 0, 1); SB(1, 1, 1); SB(1, 2, 1); SB(1, 3, 1);
  SA(1, 0, 1); SA(1, 1, 1);
  VM(8);                                   // certify B(0)+A01(0)
  __builtin_amdgcn_s_barrier();

  int kt = 0;
  for (; kt + 3 < nkt; kt += 2) {
    HALF(0, 1, kt + 1, true, kt + 2, true, VM(10), VM(8));
    HALF(1, 0, kt + 2, true, kt + 3, true, VM(10), VM(8));
  }
  // tail: tiles nkt-2 (buf0) and nkt-1 (buf1), no further prefetch
  HALF(0, 1, kt + 1, true,  kt + 2, false, VM(8), VM(2));
  HALF(1, 0, kt + 2, false, kt + 3, false, VM(0), NOOP);

  // epilogue (rows: (m&4)*32 + wm*64 + (m&3)*16 + g*4 + i)
#pragma unroll
  for (int m = 0; m < 8; ++m) {
    const int row0 = bm + ((m & 4) << 5) + (wm << 6) + ((m & 3) << 4) + (g << 2);
#pragma unroll
    for (int n = 0; n < 4; ++n) {
      const int col = bn + (wn << 6) + (n << 4) + q15;
      float bv = 0.0f;
      if constexpr (EPI != 4) bv = bias[col];
#pragma unroll
      for (int i = 0; i < 4; ++i) {
        const int mrow = row0 + i;
        float v = acc[m][n][i] + bv;
        if constexpr (EPI == 2) {
          ((__hip_bfloat16*)o0)[(size_t)mrow * N + col] =
              __float2bfloat16(0.5f * v * (1.0f + erff(v * 0.70710678118654752f)));
        } else {  // EPI == 4: raw split-K partial in bf16 (halves combine BW)
          ((__hip_bfloat16*)(blockIdx.y ? o1 : o0))[(size_t)mrow * N + col] =
              __float2bfloat16(v);
        }
      }
    }
  }
#undef SA
#undef SB
#undef RDA
#undef RDB
#undef HALF
#undef CLUSTER
#undef LGK0
#undef AOFFC
}

// ---------------------------------------------------------------------------
// split-K combine: out = bf16(p0) + bf16(p1) + bias + res (fp32 out)
// 8 elements per thread
// ---------------------------------------------------------------------------
__global__ __launch_bounds__(256)
void combine2(const __hip_bfloat16* __restrict__ p0, const __hip_bfloat16* __restrict__ p1,
              const float* __restrict__ bias, const float* __restrict__ res,
              float* __restrict__ out) {
  const size_t i = ((size_t)blockIdx.x * 256 + threadIdx.x) << 3;
  const uint4 a = *(const uint4*)(p0 + i);
  const uint4 b = *(const uint4*)(p1 + i);
  const float4 r0 = *(const float4*)(res + i);
  const float4 r1 = *(const float4*)(res + i + 4);
  const float4 bi0 = *(const float4*)(bias + (i & (DIM - 1)));
  const float4 bi1 = *(const float4*)(bias + ((i + 4) & (DIM - 1)));
  union { unsigned u; struct { unsigned short lo, hi; } s; } ua, ub;
  float4 o0, o1;
  ua.u = a.x; ub.u = b.x;
  o0.x = (float)*(__hip_bfloat16*)&ua.s.lo + (float)*(__hip_bfloat16*)&ub.s.lo + r0.x + bi0.x;
  o0.y = (float)*(__hip_bfloat16*)&ua.s.hi + (float)*(__hip_bfloat16*)&ub.s.hi + r0.y + bi0.y;
  ua.u = a.y; ub.u = b.y;
  o0.z = (float)*(__hip_bfloat16*)&ua.s.lo + (float)*(__hip_bfloat16*)&ub.s.lo + r0.z + bi0.z;
  o0.w = (float)*(__hip_bfloat16*)&ua.s.hi + (float)*(__hip_bfloat16*)&ub.s.hi + r0.w + bi0.w;
  ua.u = a.z; ub.u = b.z;
  o1.x = (float)*(__hip_bfloat16*)&ua.s.lo + (float)*(__hip_bfloat16*)&ub.s.lo + r1.x + bi1.x;
  o1.y = (float)*(__hip_bfloat16*)&ua.s.hi + (float)*(__hip_bfloat16*)&ub.s.hi + r1.y + bi1.y;
  ua.u = a.w; ub.u = b.w;
  o1.z = (float)*(__hip_bfloat16*)&ua.s.lo + (float)*(__hip_bfloat16*)&ub.s.lo + r1.z + bi1.z;
  o1.w = (float)*(__hip_bfloat16*)&ua.s.hi + (float)*(__hip_bfloat16*)&ub.s.hi + r1.w + bi1.w;
  *(float4*)(out + i) = o0;
  *(float4*)(out + i + 4) = o1;
}

// ---------------------------------------------------------------------------
// 128x128-tile GEMM (m97 structure, 2D x-fast grid, no swizzle — R1 proven,
// flat ~700 TF).  EPI 0: QKV scatter; EPI 1: + res -> fp32 (O-proj)
// ---------------------------------------------------------------------------
template <int EPI>
__global__ __launch_bounds__(256)
void gemm_bt(const __hip_bfloat16* __restrict__ A, const __hip_bfloat16* __restrict__ Bt,
             const float* __restrict__ bias, const float* __restrict__ res,
             void* __restrict__ o0, void* __restrict__ o1, void* __restrict__ o2,
             int M, int N, int K) {
  __shared__ __hip_bfloat16 As[128 * 32];
  __shared__ __hip_bfloat16 Bs[128 * 32];
  const int tid = threadIdx.x;
  const int l = tid & 63, w = tid >> 6;
  const int wr = w >> 1, wc = w & 1;
  const int g = l >> 4, q15 = l & 15;
  const int bm = blockIdx.y * 128, bn = blockIdx.x * 128;

  f32x4 acc[4][4];
#pragma unroll
  for (int a = 0; a < 4; ++a)
#pragma unroll
    for (int b = 0; b < 4; ++b) acc[a][b] = (f32x4)0.0f;

  const __hip_bfloat16* aSrc = A  + (size_t)(bm + (tid >> 2)) * K + (tid & 3) * 8;
  const __hip_bfloat16* bSrc = Bt + (size_t)(bn + (tid >> 2)) * K + (tid & 3) * 8;
  __hip_bfloat16* aDst = As + tid * 8;
  __hip_bfloat16* bDst = Bs + tid * 8;
  const size_t rowStep = (size_t)64 * K;

  for (int kt = 0; kt < K; kt += 32) {
    GL16(aSrc + kt,            aDst);
    GL16(aSrc + rowStep + kt,  aDst + 2048);
    GL16(bSrc + kt,            bDst);
    GL16(bSrc + rowStep + kt,  bDst + 2048);
    __syncthreads();
    u32x4 af[4], bf[4];
#pragma unroll
    for (int rb = 0; rb < 4; ++rb)
      af[rb] = *(const u32x4*)(As + (wr * 64 + rb * 16 + q15) * 32 + g * 8);
#pragma unroll
    for (int cb = 0; cb < 4; ++cb)
      bf[cb] = *(const u32x4*)(Bs + (wc * 64 + cb * 16 + q15) * 32 + g * 8);
#pragma unroll
    for (int rb = 0; rb < 4; ++rb)
#pragma unroll
      for (int cb = 0; cb < 4; ++cb) MFMA16(acc[rb][cb], af[rb], bf[cb]);
    __syncthreads();
  }

#pragma unroll
  for (int rb = 0; rb < 4; ++rb) {
    const int row0 = bm + wr * 64 + rb * 16 + g * 4;
#pragma unroll
    for (int cb = 0; cb < 4; ++cb) {
      const int col = bn + wc * 64 + cb * 16 + q15;
      const float bv = bias[col];
#pragma unroll
      for (int i = 0; i < 4; ++i) {
        const int m = row0 + i;
        float v = acc[rb][cb][i] + bv;
        if constexpr (EPI == 0) {
          const int sel = col >> 11, hd = col & 2047, h = hd >> 6, d = hd & 63;
          const int b = m >> 11, t = m & 2047;
          if (sel == 0) {
            // fold 1/sqrt(64) * log2(e) into Q (softmax runs in exp2 domain)
            ((__hip_bfloat16*)o0)[((size_t)(b * NH + h) * TT + t) * HD + d] =
                __float2bfloat16(v * 0.18033688011112042f);
          } else if (sel == 1) {
            ((__hip_bfloat16*)o1)[((size_t)(b * NH + h) * TT + t) * HD + d] =
                __float2bfloat16(v);
          } else {
            ((__hip_bfloat16*)o2)[((size_t)(b * NH + h) * HD + d) * TT + t] =
                __float2bfloat16(v);  // V transposed: [B,H,D,T]
          }
        } else {
          ((float*)o0)[(size_t)m * N + col] = v + res[(size_t)m * N + col];
        }
      }
    }
  }
}

// ---------------------------------------------------------------------------
// Flash attention (R5 form: exp2 softmax, cvt_pk, defer-max, v_max3,
// K-prefetch, setprio).
// ---------------------------------------------------------------------------
__global__ __launch_bounds__(256)
void attn_kernel(const __hip_bfloat16* __restrict__ Q, const __hip_bfloat16* __restrict__ Kx,
                 const __hip_bfloat16* __restrict__ Vt, __hip_bfloat16* __restrict__ out) {
  __shared__ unsigned int Plds[4][2048];  // 8KB per wave
  const int tid = threadIdx.x;
  const int l = tid & 63, w = tid >> 6;
  const int g = l >> 4, q15 = l & 15;
  const int bh = blockIdx.x >> 3;
  const int q0 = (blockIdx.x & 7) * 256 + w * 64;
  const __hip_bfloat16* Qb = Q  + (size_t)bh * TT * HD;
  const __hip_bfloat16* Kb = Kx + (size_t)bh * TT * HD;
  const __hip_bfloat16* Vb = Vt + (size_t)bh * HD * TT;
  unsigned int* Pw = Plds[w];

  u32x4 qf[4][2];
#pragma unroll
  for (int rb = 0; rb < 4; ++rb)
#pragma unroll
    for (int ks = 0; ks < 2; ++ks)
      qf[rb][ks] = *(const u32x4*)(Qb + (size_t)(q0 + rb * 16 + q15) * HD + ks * 32 + g * 8);

  f32x4 acc[4][4];  // [db][rb]
#pragma unroll
  for (int a = 0; a < 4; ++a)
#pragma unroll
    for (int b = 0; b < 4; ++b) acc[a][b] = (f32x4)0.0f;
  float mstat[4] = {-3e38f, -3e38f, -3e38f, -3e38f};
  float lstat[4] = {0.f, 0.f, 0.f, 0.f};

  u32x4 kf[2][4];
#pragma unroll
  for (int cb = 0; cb < 4; ++cb)
#pragma unroll
    for (int ks = 0; ks < 2; ++ks)
      kf[ks][cb] = *(const u32x4*)(Kb + (size_t)(cb * 16 + q15) * HD + ks * 32 + g * 8);

  for (int s0 = 0; s0 < TT; s0 += 64) {
    f32x4 st[4][4];  // [cb][rb] = S^T (exp2-domain logits)
#pragma unroll
    for (int a = 0; a < 4; ++a)
#pragma unroll
      for (int b = 0; b < 4; ++b) st[a][b] = (f32x4)0.0f;
    __builtin_amdgcn_s_setprio(1);
#pragma unroll
    for (int ks = 0; ks < 2; ++ks)
#pragma unroll
      for (int cb = 0; cb < 4; ++cb)
#pragma unroll
        for (int rb = 0; rb < 4; ++rb) MFMA16(st[cb][rb], kf[ks][cb], qf[rb][ks]);
    __builtin_amdgcn_s_setprio(0);
    // prefetch next K tile (kf dead after QK^T) — hides under softmax+PV
    if (s0 + 64 < TT) {
#pragma unroll
      for (int cb = 0; cb < 4; ++cb)
#pragma unroll
        for (int ks = 0; ks < 2; ++ks)
          kf[ks][cb] = *(const u32x4*)(Kb + (size_t)(s0 + 64 + cb * 16 + q15) * HD + ks * 32 + g * 8);
    }
#pragma unroll
    for (int rb = 0; rb < 4; ++rb) {
      // row-max tree (v_max3)
      float a0 = fmax3(st[0][rb][0], st[0][rb][1], st[0][rb][2]);
      float a1 = fmax3(st[0][rb][3], st[1][rb][0], st[1][rb][1]);
      float a2 = fmax3(st[1][rb][2], st[1][rb][3], st[2][rb][0]);
      float a3 = fmax3(st[2][rb][1], st[2][rb][2], st[2][rb][3]);
      float a4 = fmax3(st[3][rb][0], st[3][rb][1], st[3][rb][2]);
      float pm = fmax3(fmax3(a0, a1, a2), a3, fmax3(a4, st[3][rb][3], a0));
      pm = fmaxf(pm, __shfl_xor(pm, 16));
      pm = fmaxf(pm, __shfl_xor(pm, 32));
      // defer-max: only rescale when the running max grows by > 8 (log2)
      if (!__all(pm <= mstat[rb] + 8.0f)) {
        const float mnew = fmaxf(mstat[rb], pm);
        const float corr = fexp2(mstat[rb] - mnew);
        mstat[rb] = mnew;
        lstat[rb] *= corr;
#pragma unroll
        for (int db = 0; db < 4; ++db)
#pragma unroll
          for (int i = 0; i < 4; ++i) acc[db][rb][i] *= corr;
      }
      const float mcur = mstat[rb];
      float rs = 0.f;
      const int row = rb * 16 + q15;
      const int rx = row & 7;
#pragma unroll
      for (int cb = 0; cb < 4; ++cb) {
        const float p0 = fexp2(st[cb][rb][0] - mcur);
        const float p1 = fexp2(st[cb][rb][1] - mcur);
        const float p2 = fexp2(st[cb][rb][2] - mcur);
        const float p3 = fexp2(st[cb][rb][3] - mcur);
        rs += (p0 + p1) + (p2 + p3);
        const int seg = (cb * 2 + (g >> 1)) ^ rx;
        u32x2 pk = {cvtpk(p0, p1), cvtpk(p2, p3)};
        *(u32x2*)(Pw + row * 32 + seg * 4 + (g & 1) * 2) = pk;
      }
      rs += __shfl_xor(rs, 16);
      rs += __shfl_xor(rs, 32);
      lstat[rb] += rs;
    }
    // V loads batched (independent of P write settling)
    u32x4 vf[2][4];
#pragma unroll
    for (int ks2 = 0; ks2 < 2; ++ks2)
#pragma unroll
      for (int db = 0; db < 4; ++db)
        vf[ks2][db] = *(const u32x4*)(Vb + (size_t)(db * 16 + q15) * TT + s0 + ks2 * 32 + g * 8);
    u32x4 pf[2][4];
#pragma unroll
    for (int ks2 = 0; ks2 < 2; ++ks2)
#pragma unroll
      for (int rb = 0; rb < 4; ++rb) {
        const int row = rb * 16 + q15;
        const int seg = (ks2 * 4 + g) ^ (row & 7);
        pf[ks2][rb] = *(const u32x4*)(Pw + row * 32 + seg * 4);
      }
    __builtin_amdgcn_s_setprio(1);
#pragma unroll
    for (int ks2 = 0; ks2 < 2; ++ks2)
#pragma unroll
      for (int db = 0; db < 4; ++db)
#pragma unroll
        for (int rb = 0; rb < 4; ++rb) MFMA16(acc[db][rb], vf[ks2][db], pf[ks2][rb]);
    __builtin_amdgcn_s_setprio(0);
  }
  const int b = bh >> 5, hh = bh & 31;
#pragma unroll
  for (int rb = 0; rb < 4; ++rb) {
    const float inv = 1.0f / lstat[rb];
    const size_t trow = (size_t)(b * TT + q0 + rb * 16 + q15);
#pragma unroll
    for (int db = 0; db < 4; ++db) {
      u32x2 pk = {cvtpk(acc[db][rb][0] * inv, acc[db][rb][1] * inv),
                  cvtpk(acc[db][rb][2] * inv, acc[db][rb][3] * inv)};
      *(u32x2*)(out + trow * DIM + hh * 64 + db * 16 + g * 4) = pk;
    }
  }
}

// ---------------------------------------------------------------------------
extern "C" void kernel_launch(void* const* d_in, const int* in_sizes, int n_in,
                              void* d_out, int out_size, void* d_ws, size_t ws_size,
                              hipStream_t stream) {
  (void)in_sizes; (void)n_in; (void)out_size; (void)ws_size;
  const float* x     = (const float*)d_in[0];
  const float* w_qkv = (const float*)d_in[1];
  const float* b_qkv = (const float*)d_in[2];
  const float* w_o   = (const float*)d_in[3];
  const float* b_o   = (const float*)d_in[4];
  const float* g1    = (const float*)d_in[5];
  const float* be1   = (const float*)d_in[6];
  const float* w1    = (const float*)d_in[7];
  const float* b1    = (const float*)d_in[8];
  const float* w2    = (const float*)d_in[9];
  const float* b2    = (const float*)d_in[10];
  const float* g2    = (const float*)d_in[11];
  const float* be2   = (const float*)d_in[12];

  char* ws = (char*)d_ws;
  size_t off = 0;
  auto alloc = [&](size_t bytes) {
    void* p = ws + off;
    off += (bytes + 255) & ~(size_t)255;
    return p;
  };
  __hip_bfloat16* WqkvT = (__hip_bfloat16*)alloc((size_t)6144 * 2048 * 2);  // 24MB
  __hip_bfloat16* WoT   = (__hip_bfloat16*)alloc((size_t)2048 * 2048 * 2);  //  8MB
  __hip_bfloat16* W1T   = (__hip_bfloat16*)alloc((size_t)8192 * 2048 * 2);  // 32MB
  __hip_bfloat16* W2T   = (__hip_bfloat16*)alloc((size_t)2048 * 8192 * 2);  // 32MB
  __hip_bfloat16* hbuf  = (__hip_bfloat16*)alloc((size_t)MM * DIM * 2);
  float*          xres  = (float*)alloc((size_t)MM * DIM * 4);
  __hip_bfloat16* Qb    = (__hip_bfloat16*)alloc((size_t)MM * DIM * 2);
  __hip_bfloat16* Kb    = (__hip_bfloat16*)alloc((size_t)MM * DIM * 2);
  __hip_bfloat16* Vtb   = (__hip_bfloat16*)alloc((size_t)MM * DIM * 2);
  __hip_bfloat16* attno = (__hip_bfloat16*)alloc((size_t)MM * DIM * 2);
  __hip_bfloat16* f1    = Qb;  // FFN hidden aliases Q/K/Vt/attno (dead then)
  // split-K bf16 partials (16.8MB each) alias WqkvT (dead by FFN2)
  __hip_bfloat16* p0 = (__hip_bfloat16*)ws;
  __hip_bfloat16* p1 = (__hip_bfloat16*)(ws + (size_t)MM * DIM * 2);

  const dim3 tb(32, 8);
  transpose_cvt<<<dim3(6144 / 32, 2048 / 32), tb, 0, stream>>>(w_qkv, WqkvT, 2048, 6144);
  transpose_cvt<<<dim3(2048 / 32, 2048 / 32), tb, 0, stream>>>(w_o, WoT, 2048, 2048);
  transpose_cvt<<<dim3(8192 / 32, 2048 / 32), tb, 0, stream>>>(w1, W1T, 2048, 8192);
  transpose_cvt<<<dim3(2048 / 32, 8192 / 32), tb, 0, stream>>>(w2, W2T, 8192, 2048);

  ln_kernel<<<MM, 256, 0, stream>>>(x, g1, be1, hbuf);
  // QKV on the 128^2 kernel (2D x-fast grid): 48x32 = 1536 blocks, 6 exact
  // rounds -> no tail waste (gemm256's 384-block grid was 1.5 rounds).
  gemm_bt<0><<<dim3(6144 / 128, MM / 128), 256, 0, stream>>>(
      hbuf, WqkvT, b_qkv, nullptr, Qb, Kb, Vtb, MM, 6144, 2048);
  attn_kernel<<<512, 256, 0, stream>>>(Qb, Kb, Vtb, attno);
  gemm_bt<1><<<dim3(2048 / 128, MM / 128), 256, 0, stream>>>(
      attno, WoT, b_o, x, xres, nullptr, nullptr, MM, 2048, 2048);
  ln_kernel<<<MM, 256, 0, stream>>>(xres, g2, be2, hbuf);
  gemm256<2><<<dim3((8192 / 256) * (MM / 256)), 512, 0, stream>>>(
      hbuf, W1T, b1, nullptr, f1, nullptr, nullptr, MM, 8192, 2048, 32);
  gemm256<4><<<dim3((2048 / 256) * (MM / 256), 2), 512, 0, stream>>>(
      f1, W2T, nullptr, nullptr, p0, p1, nullptr, MM, 2048, 8192, 64);
  combine2<<<(MM * DIM) / 2048, 256, 0, stream>>>(p0, p1, b2, xres, (float*)d_out);
}

// Round 10
// 695.800 us; speedup vs baseline: 1.2145x; 1.0042x over previous
//
#include <hip/hip_runtime.h>
#include <hip/hip_bf16.h>

#define DIM  2048
#define DFF  8192
#define NH   32
#define HD   64
#define TT   2048
#define MM   4096   // B*T

typedef __attribute__((ext_vector_type(4))) float f32x4;
typedef __attribute__((ext_vector_type(4))) unsigned int u32x4;
typedef __attribute__((ext_vector_type(2))) unsigned int u32x2;
typedef unsigned short ushort_t;

// D = A*B + D, bf16 16x16x32 (VGPR acc)
#define MFMA16(ACC, A, B) \
  asm volatile("v_mfma_f32_16x16x32_bf16 %0, %1, %2, %0" : "+v"(ACC) : "v"(A), "v"(B))
// AGPR-accumulator variant (gemm256: keeps 128-float acc pinned in AGPRs)
#define MFMA16A(ACC, A, B) \
  asm volatile("v_mfma_f32_16x16x32_bf16 %0, %1, %2, %0" : "+a"(ACC) : "v"(A), "v"(B))

// async global->LDS, 16B per lane (dest = wave-uniform base + lane*16)
#define GL16(GP, LP)                                                     \
  __builtin_amdgcn_global_load_lds(                                      \
      (const __attribute__((address_space(1))) void*)(GP),               \
      (__attribute__((address_space(3))) void*)(LP), 16, 0, 0)

// Hand waitcnt WITHOUT a "memory" clobber; placement pinned by sched_barrier.
#define VM(N) do{ asm volatile("s_waitcnt vmcnt(" #N ")");               \
                  __builtin_amdgcn_sched_barrier(0); }while(0)
#define NOOP  ((void)0)

// opaque ds_read_b128 (invisible to SIInsertWaitcnts' LDS-DMA alias check)
template <int IMM>
__device__ __forceinline__ u32x4 dsr(unsigned a) {
  u32x4 d;
  asm volatile("ds_read_b128 %0, %1 offset:%2" : "=v"(d) : "v"(a), "i"(IMM));
  return d;
}

__device__ __forceinline__ unsigned int f2bu(float f) {
  union { __hip_bfloat16 h; unsigned short u; } c;
  c.h = __float2bfloat16(f);
  return (unsigned int)c.u;
}
// 2^x via native transcendental
__device__ __forceinline__ float fexp2(float x) {
  float r; asm("v_exp_f32 %0, %1" : "=v"(r) : "v"(x)); return r;
}
// pack two f32 -> bf16x2 in one instr (no builtin on gfx950)
__device__ __forceinline__ unsigned cvtpk(float lo, float hi) {
  unsigned r; asm("v_cvt_pk_bf16_f32 %0, %1, %2" : "=v"(r) : "v"(lo), "v"(hi));
  return r;
}
__device__ __forceinline__ float fmax3(float a, float b, float c) {
  float r; asm("v_max3_f32 %0, %1, %2, %3" : "=v"(r) : "v"(a), "v"(b), "v"(c));
  return r;
}

// ---------------------------------------------------------------------------
// Transpose + fp32->bf16 convert: in[R,C] fp32 -> out[C,R] bf16
// (16,16) block, 32x32 tile: float2 coalesced loads, packed 4-byte bf16x2
// stores (f2bu keeps RNE rounding -> numerics identical to scalar version).
// ---------------------------------------------------------------------------
__global__ __launch_bounds__(256)
void transpose_cvt(const float* __restrict__ in, __hip_bfloat16* __restrict__ out,
                   int R, int C) {
  __shared__ float tile[32][33];
  const int tx = threadIdx.x, ty = threadIdx.y;       // (16, 16)
  const int bx = blockIdx.x * 32, by = blockIdx.y * 32;
#pragma unroll
  for (int i = 0; i < 2; ++i) {
    const int row = ty + i * 16;                      // local R index
    const float2 v = *(const float2*)(in + (size_t)(by + row) * C + bx + tx * 2);
    tile[row][tx * 2]     = v.x;
    tile[row][tx * 2 + 1] = v.y;
  }
  __syncthreads();
#pragma unroll
  for (int i = 0; i < 2; ++i) {
    const int c = ty + i * 16;                        // local C index (= out row)
    const unsigned pk = f2bu(tile[tx * 2][c]) | (f2bu(tile[tx * 2 + 1][c]) << 16);
    *(unsigned*)(out + (size_t)(bx + c) * R + by + tx * 2) = pk;
  }
}

// ---------------------------------------------------------------------------
// LayerNorm: fp32 [rows, 2048] -> bf16, one block (256 thr) per row
// ---------------------------------------------------------------------------
__global__ __launch_bounds__(256)
void ln_kernel(const float* __restrict__ in, const float* __restrict__ gw,
               const float* __restrict__ bw, __hip_bfloat16* __restrict__ out) {
  const int row = blockIdx.x;
  const int t = threadIdx.x;
  const float* x = in + (size_t)row * DIM;
  const float4 v0 = ((const float4*)x)[t * 2];
  const float4 v1 = ((const float4*)x)[t * 2 + 1];
  float s  = v0.x + v0.y + v0.z + v0.w + v1.x + v1.y + v1.z + v1.w;
  float ss = v0.x*v0.x + v0.y*v0.y + v0.z*v0.z + v0.w*v0.w
           + v1.x*v1.x + v1.y*v1.y + v1.z*v1.z + v1.w*v1.w;
#pragma unroll
  for (int o = 32; o >= 1; o >>= 1) { s += __shfl_xor(s, o); ss += __shfl_xor(ss, o); }
  __shared__ float red[8];
  if ((t & 63) == 0) { red[t >> 6] = s; red[4 + (t >> 6)] = ss; }
  __syncthreads();
  s  = red[0] + red[1] + red[2] + red[3];
  ss = red[4] + red[5] + red[6] + red[7];
  const float mean = s * (1.0f / DIM);
  const float rstd = rsqrtf(ss * (1.0f / DIM) - mean * mean + 1e-5f);
  const float4 g0 = ((const float4*)gw)[t * 2], g1 = ((const float4*)gw)[t * 2 + 1];
  const float4 b0 = ((const float4*)bw)[t * 2], b1 = ((const float4*)bw)[t * 2 + 1];
  uint4 o;
  o.x = f2bu((v0.x - mean) * rstd * g0.x + b0.x) | (f2bu((v0.y - mean) * rstd * g0.y + b0.y) << 16);
  o.y = f2bu((v0.z - mean) * rstd * g0.z + b0.z) | (f2bu((v0.w - mean) * rstd * g0.w + b0.w) << 16);
  o.z = f2bu((v1.x - mean) * rstd * g1.x + b1.x) | (f2bu((v1.y - mean) * rstd * g1.y + b1.y) << 16);
  o.w = f2bu((v1.z - mean) * rstd * g1.z + b1.z) | (f2bu((v1.w - mean) * rstd * g1.w + b1.w) << 16);
  *(uint4*)((char*)out + ((size_t)row * DIM + t * 8) * 2) = o;
}

// ---------------------------------------------------------------------------
// 256x256 tile, BK=64, 8 waves, deep-pipelined 4-phase/K-tile (R6 form).
// EPI 2: gelu->bf16 (FFN1); EPI 4: split-K bf16 partial (FFN2)
// ---------------------------------------------------------------------------
template <int EPI>
__global__ __launch_bounds__(512, 2)
void gemm256(const __hip_bfloat16* __restrict__ Abf, const __hip_bfloat16* __restrict__ Btbf,
             const float* __restrict__ bias, const float* __restrict__ res,
             void* __restrict__ o0, void* __restrict__ o1, void* __restrict__ o2,
             int M, int N, int K, int nkt) {
  __shared__ ushort_t lds[2][2][16384];   // [dbuf][A=0/B=1][256*64] = 128 KiB
  const int tid = threadIdx.x;
  const int l = tid & 63, w = tid >> 6;
  const int wm = w >> 2, wn = w & 3;
  const int g = l >> 4, q15 = l & 15;

  const int nby = M >> 8;
  const int nwg = (N >> 8) * nby;
  int id = blockIdx.x;
  { // bijective XCD swizzle (m204)
    const int qq = nwg >> 3, rr = nwg & 7;
    const int xcd = id & 7, pos = id >> 3;
    id = (xcd < rr ? xcd * (qq + 1) : rr * (qq + 1) + (xcd - rr) * qq) + pos;
  }
  const int bm = (id % nby) << 8;
  const int bn = (id / nby) << 8;
  const int k0 = (EPI == 4) ? (int)blockIdx.y * (nkt << 6) : 0;

  // staging: linear LDS dest + inverse-swizzled global source (rule #21)
  const ushort_t* Au = (const ushort_t*)Abf;
  const ushort_t* Bu = (const ushort_t*)Btbf;
  const int sr = tid >> 3;                         // row within 64-row group
  const int sc = (((tid & 7) ^ (sr & 7)) << 3);    // swizzled col (elements)
  const ushort_t* aBase = Au + (size_t)(bm + sr) * K + (k0 + sc);
  const ushort_t* bBase = Bu + (size_t)(bn + sr) * K + (k0 + sc);
  const int dOff = (w << 9) + (l << 3);            // element off within group

#define SA(BUF, GRP, KT_)                                                \
  GL16(aBase + (size_t)((GRP) << 6) * K + ((KT_) << 6),                  \
       &lds[BUF][0][((GRP) << 12) + dOff])
#define SB(BUF, GRP, KT_)                                                \
  GL16(bBase + (size_t)((GRP) << 6) * K + ((KT_) << 6),                  \
       &lds[BUF][1][((GRP) << 12) + dOff])

  const unsigned lbase =
      (unsigned)(size_t)(__attribute__((address_space(3))) ushort_t*)&lds[0][0][0];
  const int x7 = q15 & 7;
  const unsigned laneA = (unsigned)(q15 * 128);
  const unsigned c0 = (unsigned)((g ^ x7) * 16);
  const unsigned c1 = (unsigned)(((4 | g) ^ x7) * 16);
  const unsigned aAk0b0 = lbase + wm * 8192 + laneA + c0;
  const unsigned aAk1b0 = lbase + wm * 8192 + laneA + c1;
  const unsigned aAk0b1 = aAk0b0 + 65536;
  const unsigned aAk1b1 = aAk1b0 + 65536;
  const unsigned aBk0b0 = lbase + 32768 + wn * 8192 + laneA + c0;
  const unsigned aBk1b0 = lbase + 32768 + wn * 8192 + laneA + c1;
  const unsigned aBk0b1 = aBk0b0 + 65536;
  const unsigned aBk1b1 = aBk1b0 + 65536;

#define AOFFC(M) (((M) & 4) * 4096 + ((M) & 3) * 2048)
#define RDA(BUF, M0, M1) do{                                             \
    af[0][0] = dsr<AOFFC(M0)>(aAk0b##BUF);                               \
    af[0][1] = dsr<AOFFC(M0)>(aAk1b##BUF);                               \
    af[1][0] = dsr<AOFFC(M1)>(aAk0b##BUF);                               \
    af[1][1] = dsr<AOFFC(M1)>(aAk1b##BUF); }while(0)
#define RDB(BUF) do{                                                     \
    bf[0][0] = dsr<0>(aBk0b##BUF);    bf[0][1] = dsr<0>(aBk1b##BUF);     \
    bf[1][0] = dsr<2048>(aBk0b##BUF); bf[1][1] = dsr<2048>(aBk1b##BUF);  \
    bf[2][0] = dsr<4096>(aBk0b##BUF); bf[2][1] = dsr<4096>(aBk1b##BUF);  \
    bf[3][0] = dsr<6144>(aBk0b##BUF); bf[3][1] = dsr<6144>(aBk1b##BUF); }while(0)

#define LGK0 do{ asm volatile("s_waitcnt lgkmcnt(0)");                   \
                 __builtin_amdgcn_sched_barrier(0); }while(0)

#define CLUSTER(R0, R1) do{                                              \
    __builtin_amdgcn_s_setprio(1);                                       \
    MFMA16A(acc[R0][0], af[0][0], bf[0][0]);                             \
    MFMA16A(acc[R0][1], af[0][0], bf[1][0]);                             \
    MFMA16A(acc[R0][2], af[0][0], bf[2][0]);                             \
    MFMA16A(acc[R0][3], af[0][0], bf[3][0]);                             \
    MFMA16A(acc[R1][0], af[1][0], bf[0][0]);                             \
    MFMA16A(acc[R1][1], af[1][0], bf[1][0]);                             \
    MFMA16A(acc[R1][2], af[1][0], bf[2][0]);                             \
    MFMA16A(acc[R1][3], af[1][0], bf[3][0]);                             \
    MFMA16A(acc[R0][0], af[0][1], bf[0][1]);                             \
    MFMA16A(acc[R0][1], af[0][1], bf[1][1]);                             \
    MFMA16A(acc[R0][2], af[0][1], bf[2][1]);                             \
    MFMA16A(acc[R0][3], af[0][1], bf[3][1]);                             \
    MFMA16A(acc[R1][0], af[1][1], bf[0][1]);                             \
    MFMA16A(acc[R1][1], af[1][1], bf[1][1]);                             \
    MFMA16A(acc[R1][2], af[1][1], bf[2][1]);                             \
    MFMA16A(acc[R1][3], af[1][1], bf[3][1]);                             \
    __builtin_amdgcn_s_setprio(0); }while(0)

#define HALF(BUF, OBUF, ktA23, PFA, ktN, PFN, W1C, W3C)                  \
  do {                                                                   \
    if (PFA) { SA(OBUF, 2, ktA23); SA(OBUF, 3, ktA23); }                 \
    RDB(BUF); RDA(BUF, 0, 1);                                            \
    __builtin_amdgcn_s_barrier();                                        \
    LGK0; CLUSTER(0, 1);                                                 \
    __builtin_amdgcn_s_barrier();                                        \
    if (PFN) { SB(BUF, 0, ktN); SB(BUF, 1, ktN); }                       \
    RDA(BUF, 2, 3);                                                      \
    __builtin_amdgcn_s_barrier();                                        \
    LGK0; CLUSTER(2, 3);                                                 \
    W1C;                                                                 \
    __builtin_amdgcn_s_barrier();                                        \
    if (PFN) { SB(BUF, 2, ktN); SB(BUF, 3, ktN); }                       \
    RDA(BUF, 4, 5);                                                      \
    __builtin_amdgcn_s_barrier();                                        \
    LGK0; CLUSTER(4, 5);                                                 \
    __builtin_amdgcn_s_barrier();                                        \
    if (PFN) { SA(BUF, 0, ktN); SA(BUF, 1, ktN); }                       \
    RDA(BUF, 6, 7);                                                      \
    __builtin_amdgcn_s_barrier();                                        \
    LGK0; CLUSTER(6, 7);                                                 \
    W3C;                                                                 \
    __builtin_amdgcn_s_barrier();                                        \
  } while (0)

  f32x4 acc[8][4];
#pragma unroll
  for (int a = 0; a < 8; ++a)
#pragma unroll
    for (int b = 0; b < 4; ++b) acc[a][b] = (f32x4)0.0f;

  u32x4 bf[4][2], af[2][2];

  // prologue (nkt >= 4): tile0 fully + tile1's B + A01 = 14 loads
  SB(0, 0, 0); SB(0, 1, 0); SB(0, 2, 0); SB(0, 3, 0);
  SA(0, 0, 0); SA(0, 1, 0); SA(0, 2, 0); SA(0, 3, 0);
  SB(1, 0, 1); SB(1, 1, 1); SB(1, 2, 1); SB(1, 3, 1);
  SA(1, 0, 1); SA(1, 1, 1);
  VM(8);                                   // certify B(0)+A01(0)
  __builtin_amdgcn_s_barrier();

  int kt = 0;
  for (; kt + 3 < nkt; kt += 2) {
    HALF(0, 1, kt + 1, true, kt + 2, true, VM(10), VM(8));
    HALF(1, 0, kt + 2, true, kt + 3, true, VM(10), VM(8));
  }
  // tail: tiles nkt-2 (buf0) and nkt-1 (buf1), no further prefetch
  HALF(0, 1, kt + 1, true,  kt + 2, false, VM(8), VM(2));
  HALF(1, 0, kt + 2, false, kt + 3, false, VM(0), NOOP);

  // epilogue (rows: (m&4)*32 + wm*64 + (m&3)*16 + g*4 + i)
#pragma unroll
  for (int m = 0; m < 8; ++m) {
    const int row0 = bm + ((m & 4) << 5) + (wm << 6) + ((m & 3) << 4) + (g << 2);
#pragma unroll
    for (int n = 0; n < 4; ++n) {
      const int col = bn + (wn << 6) + (n << 4) + q15;
      float bv = 0.0f;
      if constexpr (EPI != 4) bv = bias[col];
#pragma unroll
      for (int i = 0; i < 4; ++i) {
        const int mrow = row0 + i;
        float v = acc[m][n][i] + bv;
        if constexpr (EPI == 2) {
          ((__hip_bfloat16*)o0)[(size_t)mrow * N + col] =
              __float2bfloat16(0.5f * v * (1.0f + erff(v * 0.70710678118654752f)));
        } else {  // EPI == 4: raw split-K partial in bf16 (halves combine BW)
          ((__hip_bfloat16*)(blockIdx.y ? o1 : o0))[(size_t)mrow * N + col] =
              __float2bfloat16(v);
        }
      }
    }
  }
#undef SA
#undef SB
#undef RDA
#undef RDB
#undef HALF
#undef CLUSTER
#undef LGK0
#undef AOFFC
}

// ---------------------------------------------------------------------------
// split-K combine: out = bf16(p0) + bf16(p1) + bias + res (fp32 out)
// 8 elements per thread
// ---------------------------------------------------------------------------
__global__ __launch_bounds__(256)
void combine2(const __hip_bfloat16* __restrict__ p0, const __hip_bfloat16* __restrict__ p1,
              const float* __restrict__ bias, const float* __restrict__ res,
              float* __restrict__ out) {
  const size_t i = ((size_t)blockIdx.x * 256 + threadIdx.x) << 3;
  const uint4 a = *(const uint4*)(p0 + i);
  const uint4 b = *(const uint4*)(p1 + i);
  const float4 r0 = *(const float4*)(res + i);
  const float4 r1 = *(const float4*)(res + i + 4);
  const float4 bi0 = *(const float4*)(bias + (i & (DIM - 1)));
  const float4 bi1 = *(const float4*)(bias + ((i + 4) & (DIM - 1)));
  union { unsigned u; struct { unsigned short lo, hi; } s; } ua, ub;
  float4 o0, o1;
  ua.u = a.x; ub.u = b.x;
  o0.x = (float)*(__hip_bfloat16*)&ua.s.lo + (float)*(__hip_bfloat16*)&ub.s.lo + r0.x + bi0.x;
  o0.y = (float)*(__hip_bfloat16*)&ua.s.hi + (float)*(__hip_bfloat16*)&ub.s.hi + r0.y + bi0.y;
  ua.u = a.y; ub.u = b.y;
  o0.z = (float)*(__hip_bfloat16*)&ua.s.lo + (float)*(__hip_bfloat16*)&ub.s.lo + r0.z + bi0.z;
  o0.w = (float)*(__hip_bfloat16*)&ua.s.hi + (float)*(__hip_bfloat16*)&ub.s.hi + r0.w + bi0.w;
  ua.u = a.z; ub.u = b.z;
  o1.x = (float)*(__hip_bfloat16*)&ua.s.lo + (float)*(__hip_bfloat16*)&ub.s.lo + r1.x + bi1.x;
  o1.y = (float)*(__hip_bfloat16*)&ua.s.hi + (float)*(__hip_bfloat16*)&ub.s.hi + r1.y + bi1.y;
  ua.u = a.w; ub.u = b.w;
  o1.z = (float)*(__hip_bfloat16*)&ua.s.lo + (float)*(__hip_bfloat16*)&ub.s.lo + r1.z + bi1.z;
  o1.w = (float)*(__hip_bfloat16*)&ua.s.hi + (float)*(__hip_bfloat16*)&ub.s.hi + r1.w + bi1.w;
  *(float4*)(out + i) = o0;
  *(float4*)(out + i + 4) = o1;
}

// ---------------------------------------------------------------------------
// 128x128-tile GEMM (m97 structure, 2D x-fast grid, no swizzle — R1 proven,
// flat ~700 TF).  EPI 0: QKV scatter; EPI 1: + res -> fp32 (O-proj)
// ---------------------------------------------------------------------------
template <int EPI>
__global__ __launch_bounds__(256)
void gemm_bt(const __hip_bfloat16* __restrict__ A, const __hip_bfloat16* __restrict__ Bt,
             const float* __restrict__ bias, const float* __restrict__ res,
             void* __restrict__ o0, void* __restrict__ o1, void* __restrict__ o2,
             int M, int N, int K) {
  __shared__ __hip_bfloat16 As[128 * 32];
  __shared__ __hip_bfloat16 Bs[128 * 32];
  const int tid = threadIdx.x;
  const int l = tid & 63, w = tid >> 6;
  const int wr = w >> 1, wc = w & 1;
  const int g = l >> 4, q15 = l & 15;
  const int bm = blockIdx.y * 128, bn = blockIdx.x * 128;

  f32x4 acc[4][4];
#pragma unroll
  for (int a = 0; a < 4; ++a)
#pragma unroll
    for (int b = 0; b < 4; ++b) acc[a][b] = (f32x4)0.0f;

  const __hip_bfloat16* aSrc = A  + (size_t)(bm + (tid >> 2)) * K + (tid & 3) * 8;
  const __hip_bfloat16* bSrc = Bt + (size_t)(bn + (tid >> 2)) * K + (tid & 3) * 8;
  __hip_bfloat16* aDst = As + tid * 8;
  __hip_bfloat16* bDst = Bs + tid * 8;
  const size_t rowStep = (size_t)64 * K;

  for (int kt = 0; kt < K; kt += 32) {
    GL16(aSrc + kt,            aDst);
    GL16(aSrc + rowStep + kt,  aDst + 2048);
    GL16(bSrc + kt,            bDst);
    GL16(bSrc + rowStep + kt,  bDst + 2048);
    __syncthreads();
    u32x4 af[4], bf[4];
#pragma unroll
    for (int rb = 0; rb < 4; ++rb)
      af[rb] = *(const u32x4*)(As + (wr * 64 + rb * 16 + q15) * 32 + g * 8);
#pragma unroll
    for (int cb = 0; cb < 4; ++cb)
      bf[cb] = *(const u32x4*)(Bs + (wc * 64 + cb * 16 + q15) * 32 + g * 8);
#pragma unroll
    for (int rb = 0; rb < 4; ++rb)
#pragma unroll
      for (int cb = 0; cb < 4; ++cb) MFMA16(acc[rb][cb], af[rb], bf[cb]);
    __syncthreads();
  }

#pragma unroll
  for (int rb = 0; rb < 4; ++rb) {
    const int row0 = bm + wr * 64 + rb * 16 + g * 4;
#pragma unroll
    for (int cb = 0; cb < 4; ++cb) {
      const int col = bn + wc * 64 + cb * 16 + q15;
      const float bv = bias[col];
#pragma unroll
      for (int i = 0; i < 4; ++i) {
        const int m = row0 + i;
        float v = acc[rb][cb][i] + bv;
        if constexpr (EPI == 0) {
          const int sel = col >> 11, hd = col & 2047, h = hd >> 6, d = hd & 63;
          const int b = m >> 11, t = m & 2047;
          if (sel == 0) {
            // fold 1/sqrt(64) * log2(e) into Q (softmax runs in exp2 domain)
            ((__hip_bfloat16*)o0)[((size_t)(b * NH + h) * TT + t) * HD + d] =
                __float2bfloat16(v * 0.18033688011112042f);
          } else if (sel == 1) {
            ((__hip_bfloat16*)o1)[((size_t)(b * NH + h) * TT + t) * HD + d] =
                __float2bfloat16(v);
          } else {
            ((__hip_bfloat16*)o2)[((size_t)(b * NH + h) * HD + d) * TT + t] =
                __float2bfloat16(v);  // V transposed: [B,H,D,T]
          }
        } else {
          ((float*)o0)[(size_t)m * N + col] = v + res[(size_t)m * N + col];
        }
      }
    }
  }
}

// ---------------------------------------------------------------------------
// Flash attention (R5 form: exp2 softmax, cvt_pk, defer-max, v_max3,
// K-prefetch, setprio).
// ---------------------------------------------------------------------------
__global__ __launch_bounds__(256)
void attn_kernel(const __hip_bfloat16* __restrict__ Q, const __hip_bfloat16* __restrict__ Kx,
                 const __hip_bfloat16* __restrict__ Vt, __hip_bfloat16* __restrict__ out) {
  __shared__ unsigned int Plds[4][2048];  // 8KB per wave
  const int tid = threadIdx.x;
  const int l = tid & 63, w = tid >> 6;
  const int g = l >> 4, q15 = l & 15;
  const int bh = blockIdx.x >> 3;
  const int q0 = (blockIdx.x & 7) * 256 + w * 64;
  const __hip_bfloat16* Qb = Q  + (size_t)bh * TT * HD;
  const __hip_bfloat16* Kb = Kx + (size_t)bh * TT * HD;
  const __hip_bfloat16* Vb = Vt + (size_t)bh * HD * TT;
  unsigned int* Pw = Plds[w];

  u32x4 qf[4][2];
#pragma unroll
  for (int rb = 0; rb < 4; ++rb)
#pragma unroll
    for (int ks = 0; ks < 2; ++ks)
      qf[rb][ks] = *(const u32x4*)(Qb + (size_t)(q0 + rb * 16 + q15) * HD + ks * 32 + g * 8);

  f32x4 acc[4][4];  // [db][rb]
#pragma unroll
  for (int a = 0; a < 4; ++a)
#pragma unroll
    for (int b = 0; b < 4; ++b) acc[a][b] = (f32x4)0.0f;
  float mstat[4] = {-3e38f, -3e38f, -3e38f, -3e38f};
  float lstat[4] = {0.f, 0.f, 0.f, 0.f};

  u32x4 kf[2][4];
#pragma unroll
  for (int cb = 0; cb < 4; ++cb)
#pragma unroll
    for (int ks = 0; ks < 2; ++ks)
      kf[ks][cb] = *(const u32x4*)(Kb + (size_t)(cb * 16 + q15) * HD + ks * 32 + g * 8);

  for (int s0 = 0; s0 < TT; s0 += 64) {
    f32x4 st[4][4];  // [cb][rb] = S^T (exp2-domain logits)
#pragma unroll
    for (int a = 0; a < 4; ++a)
#pragma unroll
      for (int b = 0; b < 4; ++b) st[a][b] = (f32x4)0.0f;
    __builtin_amdgcn_s_setprio(1);
#pragma unroll
    for (int ks = 0; ks < 2; ++ks)
#pragma unroll
      for (int cb = 0; cb < 4; ++cb)
#pragma unroll
        for (int rb = 0; rb < 4; ++rb) MFMA16(st[cb][rb], kf[ks][cb], qf[rb][ks]);
    __builtin_amdgcn_s_setprio(0);
    // prefetch next K tile (kf dead after QK^T) — hides under softmax+PV
    if (s0 + 64 < TT) {
#pragma unroll
      for (int cb = 0; cb < 4; ++cb)
#pragma unroll
        for (int ks = 0; ks < 2; ++ks)
          kf[ks][cb] = *(const u32x4*)(Kb + (size_t)(s0 + 64 + cb * 16 + q15) * HD + ks * 32 + g * 8);
    }
#pragma unroll
    for (int rb = 0; rb < 4; ++rb) {
      // row-max tree (v_max3)
      float a0 = fmax3(st[0][rb][0], st[0][rb][1], st[0][rb][2]);
      float a1 = fmax3(st[0][rb][3], st[1][rb][0], st[1][rb][1]);
      float a2 = fmax3(st[1][rb][2], st[1][rb][3], st[2][rb][0]);
      float a3 = fmax3(st[2][rb][1], st[2][rb][2], st[2][rb][3]);
      float a4 = fmax3(st[3][rb][0], st[3][rb][1], st[3][rb][2]);
      float pm = fmax3(fmax3(a0, a1, a2), a3, fmax3(a4, st[3][rb][3], a0));
      pm = fmaxf(pm, __shfl_xor(pm, 16));
      pm = fmaxf(pm, __shfl_xor(pm, 32));
      // defer-max: only rescale when the running max grows by > 8 (log2)
      if (!__all(pm <= mstat[rb] + 8.0f)) {
        const float mnew = fmaxf(mstat[rb], pm);
        const float corr = fexp2(mstat[rb] - mnew);
        mstat[rb] = mnew;
        lstat[rb] *= corr;
#pragma unroll
        for (int db = 0; db < 4; ++db)
#pragma unroll
          for (int i = 0; i < 4; ++i) acc[db][rb][i] *= corr;
      }
      const float mcur = mstat[rb];
      float rs = 0.f;
      const int row = rb * 16 + q15;
      const int rx = row & 7;
#pragma unroll
      for (int cb = 0; cb < 4; ++cb) {
        const float p0 = fexp2(st[cb][rb][0] - mcur);
        const float p1 = fexp2(st[cb][rb][1] - mcur);
        const float p2 = fexp2(st[cb][rb][2] - mcur);
        const float p3 = fexp2(st[cb][rb][3] - mcur);
        rs += (p0 + p1) + (p2 + p3);
        const int seg = (cb * 2 + (g >> 1)) ^ rx;
        u32x2 pk = {cvtpk(p0, p1), cvtpk(p2, p3)};
        *(u32x2*)(Pw + row * 32 + seg * 4 + (g & 1) * 2) = pk;
      }
      rs += __shfl_xor(rs, 16);
      rs += __shfl_xor(rs, 32);
      lstat[rb] += rs;
    }
    // V loads batched (independent of P write settling)
    u32x4 vf[2][4];
#pragma unroll
    for (int ks2 = 0; ks2 < 2; ++ks2)
#pragma unroll
      for (int db = 0; db < 4; ++db)
        vf[ks2][db] = *(const u32x4*)(Vb + (size_t)(db * 16 + q15) * TT + s0 + ks2 * 32 + g * 8);
    u32x4 pf[2][4];
#pragma unroll
    for (int ks2 = 0; ks2 < 2; ++ks2)
#pragma unroll
      for (int rb = 0; rb < 4; ++rb) {
        const int row = rb * 16 + q15;
        const int seg = (ks2 * 4 + g) ^ (row & 7);
        pf[ks2][rb] = *(const u32x4*)(Pw + row * 32 + seg * 4);
      }
    __builtin_amdgcn_s_setprio(1);
#pragma unroll
    for (int ks2 = 0; ks2 < 2; ++ks2)
#pragma unroll
      for (int db = 0; db < 4; ++db)
#pragma unroll
        for (int rb = 0; rb < 4; ++rb) MFMA16(acc[db][rb], vf[ks2][db], pf[ks2][rb]);
    __builtin_amdgcn_s_setprio(0);
  }
  const int b = bh >> 5, hh = bh & 31;
#pragma unroll
  for (int rb = 0; rb < 4; ++rb) {
    const float inv = 1.0f / lstat[rb];
    const size_t trow = (size_t)(b * TT + q0 + rb * 16 + q15);
#pragma unroll
    for (int db = 0; db < 4; ++db) {
      u32x2 pk = {cvtpk(acc[db][rb][0] * inv, acc[db][rb][1] * inv),
                  cvtpk(acc[db][rb][2] * inv, acc[db][rb][3] * inv)};
      *(u32x2*)(out + trow * DIM + hh * 64 + db * 16 + g * 4) = pk;
    }
  }
}

// ---------------------------------------------------------------------------
extern "C" void kernel_launch(void* const* d_in, const int* in_sizes, int n_in,
                              void* d_out, int out_size, void* d_ws, size_t ws_size,
                              hipStream_t stream) {
  (void)in_sizes; (void)n_in; (void)out_size; (void)ws_size;
  const float* x     = (const float*)d_in[0];
  const float* w_qkv = (const float*)d_in[1];
  const float* b_qkv = (const float*)d_in[2];
  const float* w_o   = (const float*)d_in[3];
  const float* b_o   = (const float*)d_in[4];
  const float* g1    = (const float*)d_in[5];
  const float* be1   = (const float*)d_in[6];
  const float* w1    = (const float*)d_in[7];
  const float* b1    = (const float*)d_in[8];
  const float* w2    = (const float*)d_in[9];
  const float* b2    = (const float*)d_in[10];
  const float* g2    = (const float*)d_in[11];
  const float* be2   = (const float*)d_in[12];

  char* ws = (char*)d_ws;
  size_t off = 0;
  auto alloc = [&](size_t bytes) {
    void* p = ws + off;
    off += (bytes + 255) & ~(size_t)255;
    return p;
  };
  __hip_bfloat16* WqkvT = (__hip_bfloat16*)alloc((size_t)6144 * 2048 * 2);  // 24MB
  __hip_bfloat16* WoT   = (__hip_bfloat16*)alloc((size_t)2048 * 2048 * 2);  //  8MB
  __hip_bfloat16* W1T   = (__hip_bfloat16*)alloc((size_t)8192 * 2048 * 2);  // 32MB
  __hip_bfloat16* W2T   = (__hip_bfloat16*)alloc((size_t)2048 * 8192 * 2);  // 32MB
  __hip_bfloat16* hbuf  = (__hip_bfloat16*)alloc((size_t)MM * DIM * 2);
  float*          xres  = (float*)alloc((size_t)MM * DIM * 4);
  __hip_bfloat16* Qb    = (__hip_bfloat16*)alloc((size_t)MM * DIM * 2);
  __hip_bfloat16* Kb    = (__hip_bfloat16*)alloc((size_t)MM * DIM * 2);
  __hip_bfloat16* Vtb   = (__hip_bfloat16*)alloc((size_t)MM * DIM * 2);
  __hip_bfloat16* attno = (__hip_bfloat16*)alloc((size_t)MM * DIM * 2);
  __hip_bfloat16* f1    = Qb;  // FFN hidden aliases Q/K/Vt/attno (dead then)
  // split-K bf16 partials (16.8MB each) alias WqkvT (dead by FFN2)
  __hip_bfloat16* p0 = (__hip_bfloat16*)ws;
  __hip_bfloat16* p1 = (__hip_bfloat16*)(ws + (size_t)MM * DIM * 2);

  const dim3 tb(16, 16);
  transpose_cvt<<<dim3(6144 / 32, 2048 / 32), tb, 0, stream>>>(w_qkv, WqkvT, 2048, 6144);
  transpose_cvt<<<dim3(2048 / 32, 2048 / 32), tb, 0, stream>>>(w_o, WoT, 2048, 2048);
  transpose_cvt<<<dim3(8192 / 32, 2048 / 32), tb, 0, stream>>>(w1, W1T, 2048, 8192);
  transpose_cvt<<<dim3(2048 / 32, 8192 / 32), tb, 0, stream>>>(w2, W2T, 8192, 2048);

  ln_kernel<<<MM, 256, 0, stream>>>(x, g1, be1, hbuf);
  // QKV on the 128^2 kernel (2D x-fast grid): 48x32 = 1536 blocks, 6 exact
  // rounds -> no tail waste.
  gemm_bt<0><<<dim3(6144 / 128, MM / 128), 256, 0, stream>>>(
      hbuf, WqkvT, b_qkv, nullptr, Qb, Kb, Vtb, MM, 6144, 2048);
  attn_kernel<<<512, 256, 0, stream>>>(Qb, Kb, Vtb, attno);
  gemm_bt<1><<<dim3(2048 / 128, MM / 128), 256, 0, stream>>>(
      attno, WoT, b_o, x, xres, nullptr, nullptr, MM, 2048, 2048);
  ln_kernel<<<MM, 256, 0, stream>>>(xres, g2, be2, hbuf);
  gemm256<2><<<dim3((8192 / 256) * (MM / 256)), 512, 0, stream>>>(
      hbuf, W1T, b1, nullptr, f1, nullptr, nullptr, MM, 8192, 2048, 32);
  gemm256<4><<<dim3((2048 / 256) * (MM / 256), 2), 512, 0, stream>>>(
      f1, W2T, nullptr, nullptr, p0, p1, nullptr, MM, 2048, 8192, 64);
  combine2<<<(MM * DIM) / 2048, 256, 0, stream>>>(p0, p1, b2, xres, (float*)d_out);
}

// Round 12
// 695.567 us; speedup vs baseline: 1.2149x; 1.0003x over previous
//
#include <hip/hip_runtime.h>
#include <hip/hip_bf16.h>

#define DIM  2048
#define DFF  8192
#define NH   32
#define HD   64
#define TT   2048
#define MM   4096   // B*T

typedef __attribute__((ext_vector_type(4))) float f32x4;
typedef __attribute__((ext_vector_type(4))) unsigned int u32x4;
typedef __attribute__((ext_vector_type(2))) unsigned int u32x2;
typedef unsigned short ushort_t;

// D = A*B + D, bf16 16x16x32 (VGPR acc)
#define MFMA16(ACC, A, B) \
  asm volatile("v_mfma_f32_16x16x32_bf16 %0, %1, %2, %0" : "+v"(ACC) : "v"(A), "v"(B))
// AGPR-accumulator variant (gemm256: keeps 128-float acc pinned in AGPRs)
#define MFMA16A(ACC, A, B) \
  asm volatile("v_mfma_f32_16x16x32_bf16 %0, %1, %2, %0" : "+a"(ACC) : "v"(A), "v"(B))

// async global->LDS, 16B per lane (dest = wave-uniform base + lane*16)
#define GL16(GP, LP)                                                     \
  __builtin_amdgcn_global_load_lds(                                      \
      (const __attribute__((address_space(1))) void*)(GP),               \
      (__attribute__((address_space(3))) void*)(LP), 16, 0, 0)

// Hand waitcnt WITHOUT a "memory" clobber; placement pinned by sched_barrier.
#define VM(N) do{ asm volatile("s_waitcnt vmcnt(" #N ")");               \
                  __builtin_amdgcn_sched_barrier(0); }while(0)
#define NOOP  ((void)0)

// opaque ds_read_b128 (invisible to SIInsertWaitcnts' LDS-DMA alias check)
template <int IMM>
__device__ __forceinline__ u32x4 dsr(unsigned a) {
  u32x4 d;
  asm volatile("ds_read_b128 %0, %1 offset:%2" : "=v"(d) : "v"(a), "i"(IMM));
  return d;
}

__device__ __forceinline__ unsigned int f2bu(float f) {
  union { __hip_bfloat16 h; unsigned short u; } c;
  c.h = __float2bfloat16(f);
  return (unsigned int)c.u;
}
// 2^x via native transcendental
__device__ __forceinline__ float fexp2(float x) {
  float r; asm("v_exp_f32 %0, %1" : "=v"(r) : "v"(x)); return r;
}
// pack two f32 -> bf16x2 in one instr (no builtin on gfx950)
__device__ __forceinline__ unsigned cvtpk(float lo, float hi) {
  unsigned r; asm("v_cvt_pk_bf16_f32 %0, %1, %2" : "=v"(r) : "v"(lo), "v"(hi));
  return r;
}
__device__ __forceinline__ float fmax3(float a, float b, float c) {
  float r; asm("v_max3_f32 %0, %1, %2, %3" : "=v"(r) : "v"(a), "v"(b), "v"(c));
  return r;
}

// ---------------------------------------------------------------------------
// Transpose + fp32->bf16 convert: in[R,C] fp32 -> out[C,R] bf16
// (16,16) block, 32x32 tile: float2 coalesced loads, packed 4-byte bf16x2
// stores (f2bu keeps RNE rounding -> numerics identical to scalar version).
// ---------------------------------------------------------------------------
__global__ __launch_bounds__(256)
void transpose_cvt(const float* __restrict__ in, __hip_bfloat16* __restrict__ out,
                   int R, int C) {
  __shared__ float tile[32][33];
  const int tx = threadIdx.x, ty = threadIdx.y;       // (16, 16)
  const int bx = blockIdx.x * 32, by = blockIdx.y * 32;
#pragma unroll
  for (int i = 0; i < 2; ++i) {
    const int row = ty + i * 16;                      // local R index
    const float2 v = *(const float2*)(in + (size_t)(by + row) * C + bx + tx * 2);
    tile[row][tx * 2]     = v.x;
    tile[row][tx * 2 + 1] = v.y;
  }
  __syncthreads();
#pragma unroll
  for (int i = 0; i < 2; ++i) {
    const int c = ty + i * 16;                        // local C index (= out row)
    const unsigned pk = f2bu(tile[tx * 2][c]) | (f2bu(tile[tx * 2 + 1][c]) << 16);
    *(unsigned*)(out + (size_t)(bx + c) * R + by + tx * 2) = pk;
  }
}

// ---------------------------------------------------------------------------
// LayerNorm: fp32 [rows, 2048] -> bf16, one block (256 thr) per row
// ---------------------------------------------------------------------------
__global__ __launch_bounds__(256)
void ln_kernel(const float* __restrict__ in, const float* __restrict__ gw,
               const float* __restrict__ bw, __hip_bfloat16* __restrict__ out) {
  const int row = blockIdx.x;
  const int t = threadIdx.x;
  const float* x = in + (size_t)row * DIM;
  const float4 v0 = ((const float4*)x)[t * 2];
  const float4 v1 = ((const float4*)x)[t * 2 + 1];
  float s  = v0.x + v0.y + v0.z + v0.w + v1.x + v1.y + v1.z + v1.w;
  float ss = v0.x*v0.x + v0.y*v0.y + v0.z*v0.z + v0.w*v0.w
           + v1.x*v1.x + v1.y*v1.y + v1.z*v1.z + v1.w*v1.w;
#pragma unroll
  for (int o = 32; o >= 1; o >>= 1) { s += __shfl_xor(s, o); ss += __shfl_xor(ss, o); }
  __shared__ float red[8];
  if ((t & 63) == 0) { red[t >> 6] = s; red[4 + (t >> 6)] = ss; }
  __syncthreads();
  s  = red[0] + red[1] + red[2] + red[3];
  ss = red[4] + red[5] + red[6] + red[7];
  const float mean = s * (1.0f / DIM);
  const float rstd = rsqrtf(ss * (1.0f / DIM) - mean * mean + 1e-5f);
  const float4 g0 = ((const float4*)gw)[t * 2], g1 = ((const float4*)gw)[t * 2 + 1];
  const float4 b0 = ((const float4*)bw)[t * 2], b1 = ((const float4*)bw)[t * 2 + 1];
  uint4 o;
  o.x = f2bu((v0.x - mean) * rstd * g0.x + b0.x) | (f2bu((v0.y - mean) * rstd * g0.y + b0.y) << 16);
  o.y = f2bu((v0.z - mean) * rstd * g0.z + b0.z) | (f2bu((v0.w - mean) * rstd * g0.w + b0.w) << 16);
  o.z = f2bu((v1.x - mean) * rstd * g1.x + b1.x) | (f2bu((v1.y - mean) * rstd * g1.y + b1.y) << 16);
  o.w = f2bu((v1.z - mean) * rstd * g1.z + b1.z) | (f2bu((v1.w - mean) * rstd * g1.w + b1.w) << 16);
  *(uint4*)((char*)out + ((size_t)row * DIM + t * 8) * 2) = o;
}

// ---------------------------------------------------------------------------
// 256x256 tile, BK=64, 8 waves, deep-pipelined 4-phase/K-tile (R6 form).
// EPI 2: gelu->bf16 (FFN1); EPI 4: split-K bf16 partial (FFN2)
// ---------------------------------------------------------------------------
template <int EPI>
__global__ __launch_bounds__(512, 2)
void gemm256(const __hip_bfloat16* __restrict__ Abf, const __hip_bfloat16* __restrict__ Btbf,
             const float* __restrict__ bias, const float* __restrict__ res,
             void* __restrict__ o0, void* __restrict__ o1, void* __restrict__ o2,
             int M, int N, int K, int nkt) {
  __shared__ ushort_t lds[2][2][16384];   // [dbuf][A=0/B=1][256*64] = 128 KiB
  const int tid = threadIdx.x;
  const int l = tid & 63, w = tid >> 6;
  const int wm = w >> 2, wn = w & 3;
  const int g = l >> 4, q15 = l & 15;

  const int nby = M >> 8;
  const int nwg = (N >> 8) * nby;
  int id = blockIdx.x;
  { // bijective XCD swizzle (m204)
    const int qq = nwg >> 3, rr = nwg & 7;
    const int xcd = id & 7, pos = id >> 3;
    id = (xcd < rr ? xcd * (qq + 1) : rr * (qq + 1) + (xcd - rr) * qq) + pos;
  }
  const int bm = (id % nby) << 8;
  const int bn = (id / nby) << 8;
  const int k0 = (EPI == 4) ? (int)blockIdx.y * (nkt << 6) : 0;

  // staging: linear LDS dest + inverse-swizzled global source (rule #21)
  const ushort_t* Au = (const ushort_t*)Abf;
  const ushort_t* Bu = (const ushort_t*)Btbf;
  const int sr = tid >> 3;                         // row within 64-row group
  const int sc = (((tid & 7) ^ (sr & 7)) << 3);    // swizzled col (elements)
  const ushort_t* aBase = Au + (size_t)(bm + sr) * K + (k0 + sc);
  const ushort_t* bBase = Bu + (size_t)(bn + sr) * K + (k0 + sc);
  const int dOff = (w << 9) + (l << 3);            // element off within group

#define SA(BUF, GRP, KT_)                                                \
  GL16(aBase + (size_t)((GRP) << 6) * K + ((KT_) << 6),                  \
       &lds[BUF][0][((GRP) << 12) + dOff])
#define SB(BUF, GRP, KT_)                                                \
  GL16(bBase + (size_t)((GRP) << 6) * K + ((KT_) << 6),                  \
       &lds[BUF][1][((GRP) << 12) + dOff])

  const unsigned lbase =
      (unsigned)(size_t)(__attribute__((address_space(3))) ushort_t*)&lds[0][0][0];
  const int x7 = q15 & 7;
  const unsigned laneA = (unsigned)(q15 * 128);
  const unsigned c0 = (unsigned)((g ^ x7) * 16);
  const unsigned c1 = (unsigned)(((4 | g) ^ x7) * 16);
  const unsigned aAk0b0 = lbase + wm * 8192 + laneA + c0;
  const unsigned aAk1b0 = lbase + wm * 8192 + laneA + c1;
  const unsigned aAk0b1 = aAk0b0 + 65536;
  const unsigned aAk1b1 = aAk1b0 + 65536;
  const unsigned aBk0b0 = lbase + 32768 + wn * 8192 + laneA + c0;
  const unsigned aBk1b0 = lbase + 32768 + wn * 8192 + laneA + c1;
  const unsigned aBk0b1 = aBk0b0 + 65536;
  const unsigned aBk1b1 = aBk1b0 + 65536;

#define AOFFC(M) (((M) & 4) * 4096 + ((M) & 3) * 2048)
#define RDA(BUF, M0, M1) do{                                             \
    af[0][0] = dsr<AOFFC(M0)>(aAk0b##BUF);                               \
    af[0][1] = dsr<AOFFC(M0)>(aAk1b##BUF);                               \
    af[1][0] = dsr<AOFFC(M1)>(aAk0b##BUF);                               \
    af[1][1] = dsr<AOFFC(M1)>(aAk1b##BUF); }while(0)
#define RDB(BUF) do{                                                     \
    bf[0][0] = dsr<0>(aBk0b##BUF);    bf[0][1] = dsr<0>(aBk1b##BUF);     \
    bf[1][0] = dsr<2048>(aBk0b##BUF); bf[1][1] = dsr<2048>(aBk1b##BUF);  \
    bf[2][0] = dsr<4096>(aBk0b##BUF); bf[2][1] = dsr<4096>(aBk1b##BUF);  \
    bf[3][0] = dsr<6144>(aBk0b##BUF); bf[3][1] = dsr<6144>(aBk1b##BUF); }while(0)

#define LGK0 do{ asm volatile("s_waitcnt lgkmcnt(0)");                   \
                 __builtin_amdgcn_sched_barrier(0); }while(0)

#define CLUSTER(R0, R1) do{                                              \
    __builtin_amdgcn_s_setprio(1);                                       \
    MFMA16A(acc[R0][0], af[0][0], bf[0][0]);                             \
    MFMA16A(acc[R0][1], af[0][0], bf[1][0]);                             \
    MFMA16A(acc[R0][2], af[0][0], bf[2][0]);                             \
    MFMA16A(acc[R0][3], af[0][0], bf[3][0]);                             \
    MFMA16A(acc[R1][0], af[1][0], bf[0][0]);                             \
    MFMA16A(acc[R1][1], af[1][0], bf[1][0]);                             \
    MFMA16A(acc[R1][2], af[1][0], bf[2][0]);                             \
    MFMA16A(acc[R1][3], af[1][0], bf[3][0]);                             \
    MFMA16A(acc[R0][0], af[0][1], bf[0][1]);                             \
    MFMA16A(acc[R0][1], af[0][1], bf[1][1]);                             \
    MFMA16A(acc[R0][2], af[0][1], bf[2][1]);                             \
    MFMA16A(acc[R0][3], af[0][1], bf[3][1]);                             \
    MFMA16A(acc[R1][0], af[1][1], bf[0][1]);                             \
    MFMA16A(acc[R1][1], af[1][1], bf[1][1]);                             \
    MFMA16A(acc[R1][2], af[1][1], bf[2][1]);                             \
    MFMA16A(acc[R1][3], af[1][1], bf[3][1]);                             \
    __builtin_amdgcn_s_setprio(0); }while(0)

#define HALF(BUF, OBUF, ktA23, PFA, ktN, PFN, W1C, W3C)                  \
  do {                                                                   \
    if (PFA) { SA(OBUF, 2, ktA23); SA(OBUF, 3, ktA23); }                 \
    RDB(BUF); RDA(BUF, 0, 1);                                            \
    __builtin_amdgcn_s_barrier();                                        \
    LGK0; CLUSTER(0, 1);                                                 \
    __builtin_amdgcn_s_barrier();                                        \
    if (PFN) { SB(BUF, 0, ktN); SB(BUF, 1, ktN); }                       \
    RDA(BUF, 2, 3);                                                      \
    __builtin_amdgcn_s_barrier();                                        \
    LGK0; CLUSTER(2, 3);                                                 \
    W1C;                                                                 \
    __builtin_amdgcn_s_barrier();                                        \
    if (PFN) { SB(BUF, 2, ktN); SB(BUF, 3, ktN); }                       \
    RDA(BUF, 4, 5);                                                      \
    __builtin_amdgcn_s_barrier();                                        \
    LGK0; CLUSTER(4, 5);                                                 \
    __builtin_amdgcn_s_barrier();                                        \
    if (PFN) { SA(BUF, 0, ktN); SA(BUF, 1, ktN); }                       \
    RDA(BUF, 6, 7);                                                      \
    __builtin_amdgcn_s_barrier();                                        \
    LGK0; CLUSTER(6, 7);                                                 \
    W3C;                                                                 \
    __builtin_amdgcn_s_barrier();                                        \
  } while (0)

  f32x4 acc[8][4];
#pragma unroll
  for (int a = 0; a < 8; ++a)
#pragma unroll
    for (int b = 0; b < 4; ++b) acc[a][b] = (f32x4)0.0f;

  u32x4 bf[4][2], af[2][2];

  // prologue (nkt >= 4): tile0 fully + tile1's B + A01 = 14 loads
  SB(0, 0, 0); SB(0, 1, 0); SB(0, 2, 0); SB(0, 3, 0);
  SA(0, 0, 0); SA(0, 1, 0); SA(0, 2, 0); SA(0, 3, 0);
  SB(1, 0, 1); SB(1, 1, 1); SB(1, 2, 1); SB(1, 3, 1);
  SA(1, 0, 1); SA(1, 1, 1);
  VM(8);                                   // certify B(0)+A01(0)
  __builtin_amdgcn_s_barrier();

  int kt = 0;
  for (; kt + 3 < nkt; kt += 2) {
    HALF(0, 1, kt + 1, true, kt + 2, true, VM(10), VM(8));
    HALF(1, 0, kt + 2, true, kt + 3, true, VM(10), VM(8));
  }
  // tail: tiles nkt-2 (buf0) and nkt-1 (buf1), no further prefetch
  HALF(0, 1, kt + 1, true,  kt + 2, false, VM(8), VM(2));
  HALF(1, 0, kt + 2, false, kt + 3, false, VM(0), NOOP);

  // epilogue (rows: (m&4)*32 + wm*64 + (m&3)*16 + g*4 + i)
#pragma unroll
  for (int m = 0; m < 8; ++m) {
    const int row0 = bm + ((m & 4) << 5) + (wm << 6) + ((m & 3) << 4) + (g << 2);
#pragma unroll
    for (int n = 0; n < 4; ++n) {
      const int col = bn + (wn << 6) + (n << 4) + q15;
      float bv = 0.0f;
      if constexpr (EPI != 4) bv = bias[col];
#pragma unroll
      for (int i = 0; i < 4; ++i) {
        const int mrow = row0 + i;
        float v = acc[m][n][i] + bv;
        if constexpr (EPI == 2) {
          ((__hip_bfloat16*)o0)[(size_t)mrow * N + col] =
              __float2bfloat16(0.5f * v * (1.0f + erff(v * 0.70710678118654752f)));
        } else {  // EPI == 4: raw split-K partial in bf16 (halves combine BW)
          ((__hip_bfloat16*)(blockIdx.y ? o1 : o0))[(size_t)mrow * N + col] =
              __float2bfloat16(v);
        }
      }
    }
  }
#undef SA
#undef SB
#undef RDA
#undef RDB
#undef HALF
#undef CLUSTER
#undef LGK0
#undef AOFFC
}

// ---------------------------------------------------------------------------
// split-K combine: out = bf16(p0) + bf16(p1) + bias + res (fp32 out)
// 8 elements per thread
// ---------------------------------------------------------------------------
__global__ __launch_bounds__(256)
void combine2(const __hip_bfloat16* __restrict__ p0, const __hip_bfloat16* __restrict__ p1,
              const float* __restrict__ bias, const float* __restrict__ res,
              float* __restrict__ out) {
  const size_t i = ((size_t)blockIdx.x * 256 + threadIdx.x) << 3;
  const uint4 a = *(const uint4*)(p0 + i);
  const uint4 b = *(const uint4*)(p1 + i);
  const float4 r0 = *(const float4*)(res + i);
  const float4 r1 = *(const float4*)(res + i + 4);
  const float4 bi0 = *(const float4*)(bias + (i & (DIM - 1)));
  const float4 bi1 = *(const float4*)(bias + ((i + 4) & (DIM - 1)));
  union { unsigned u; struct { unsigned short lo, hi; } s; } ua, ub;
  float4 o0, o1;
  ua.u = a.x; ub.u = b.x;
  o0.x = (float)*(__hip_bfloat16*)&ua.s.lo + (float)*(__hip_bfloat16*)&ub.s.lo + r0.x + bi0.x;
  o0.y = (float)*(__hip_bfloat16*)&ua.s.hi + (float)*(__hip_bfloat16*)&ub.s.hi + r0.y + bi0.y;
  ua.u = a.y; ub.u = b.y;
  o0.z = (float)*(__hip_bfloat16*)&ua.s.lo + (float)*(__hip_bfloat16*)&ub.s.lo + r0.z + bi0.z;
  o0.w = (float)*(__hip_bfloat16*)&ua.s.hi + (float)*(__hip_bfloat16*)&ub.s.hi + r0.w + bi0.w;
  ua.u = a.z; ub.u = b.z;
  o1.x = (float)*(__hip_bfloat16*)&ua.s.lo + (float)*(__hip_bfloat16*)&ub.s.lo + r1.x + bi1.x;
  o1.y = (float)*(__hip_bfloat16*)&ua.s.hi + (float)*(__hip_bfloat16*)&ub.s.hi + r1.y + bi1.y;
  ua.u = a.w; ub.u = b.w;
  o1.z = (float)*(__hip_bfloat16*)&ua.s.lo + (float)*(__hip_bfloat16*)&ub.s.lo + r1.z + bi1.z;
  o1.w = (float)*(__hip_bfloat16*)&ua.s.hi + (float)*(__hip_bfloat16*)&ub.s.hi + r1.w + bi1.w;
  *(float4*)(out + i) = o0;
  *(float4*)(out + i + 4) = o1;
}

// ---------------------------------------------------------------------------
// 128x128-tile GEMM (m97 structure, 2D x-fast grid, no swizzle — R1 proven,
// flat ~700 TF).  EPI 0: QKV scatter; EPI 1: + res -> fp32 (O-proj)
// ---------------------------------------------------------------------------
template <int EPI>
__global__ __launch_bounds__(256)
void gemm_bt(const __hip_bfloat16* __restrict__ A, const __hip_bfloat16* __restrict__ Bt,
             const float* __restrict__ bias, const float* __restrict__ res,
             void* __restrict__ o0, void* __restrict__ o1, void* __restrict__ o2,
             int M, int N, int K) {
  __shared__ __hip_bfloat16 As[128 * 32];
  __shared__ __hip_bfloat16 Bs[128 * 32];
  const int tid = threadIdx.x;
  const int l = tid & 63, w = tid >> 6;
  const int wr = w >> 1, wc = w & 1;
  const int g = l >> 4, q15 = l & 15;
  const int bm = blockIdx.y * 128, bn = blockIdx.x * 128;

  f32x4 acc[4][4];
#pragma unroll
  for (int a = 0; a < 4; ++a)
#pragma unroll
    for (int b = 0; b < 4; ++b) acc[a][b] = (f32x4)0.0f;

  const __hip_bfloat16* aSrc = A  + (size_t)(bm + (tid >> 2)) * K + (tid & 3) * 8;
  const __hip_bfloat16* bSrc = Bt + (size_t)(bn + (tid >> 2)) * K + (tid & 3) * 8;
  __hip_bfloat16* aDst = As + tid * 8;
  __hip_bfloat16* bDst = Bs + tid * 8;
  const size_t rowStep = (size_t)64 * K;

  for (int kt = 0; kt < K; kt += 32) {
    GL16(aSrc + kt,            aDst);
    GL16(aSrc + rowStep + kt,  aDst + 2048);
    GL16(bSrc + kt,            bDst);
    GL16(bSrc + rowStep + kt,  bDst + 2048);
    __syncthreads();
    u32x4 af[4], bf[4];
#pragma unroll
    for (int rb = 0; rb < 4; ++rb)
      af[rb] = *(const u32x4*)(As + (wr * 64 + rb * 16 + q15) * 32 + g * 8);
#pragma unroll
    for (int cb = 0; cb < 4; ++cb)
      bf[cb] = *(const u32x4*)(Bs + (wc * 64 + cb * 16 + q15) * 32 + g * 8);
#pragma unroll
    for (int rb = 0; rb < 4; ++rb)
#pragma unroll
      for (int cb = 0; cb < 4; ++cb) MFMA16(acc[rb][cb], af[rb], bf[cb]);
    __syncthreads();
  }

#pragma unroll
  for (int rb = 0; rb < 4; ++rb) {
    const int row0 = bm + wr * 64 + rb * 16 + g * 4;
#pragma unroll
    for (int cb = 0; cb < 4; ++cb) {
      const int col = bn + wc * 64 + cb * 16 + q15;
      const float bv = bias[col];
#pragma unroll
      for (int i = 0; i < 4; ++i) {
        const int m = row0 + i;
        float v = acc[rb][cb][i] + bv;
        if constexpr (EPI == 0) {
          const int sel = col >> 11, hd = col & 2047, h = hd >> 6, d = hd & 63;
          const int b = m >> 11, t = m & 2047;
          if (sel == 0) {
            // fold 1/sqrt(64) * log2(e) into Q (softmax runs in exp2 domain)
            ((__hip_bfloat16*)o0)[((size_t)(b * NH + h) * TT + t) * HD + d] =
                __float2bfloat16(v * 0.18033688011112042f);
          } else if (sel == 1) {
            ((__hip_bfloat16*)o1)[((size_t)(b * NH + h) * TT + t) * HD + d] =
                __float2bfloat16(v);
          } else {
            ((__hip_bfloat16*)o2)[((size_t)(b * NH + h) * HD + d) * TT + t] =
                __float2bfloat16(v);  // V transposed: [B,H,D,T]
          }
        } else {
          ((float*)o0)[(size_t)m * N + col] = v + res[(size_t)m * N + col];
        }
      }
    }
  }
}

// ---------------------------------------------------------------------------
// Flash attention (R5 form: exp2 softmax, cvt_pk, defer-max, v_max3,
// K-prefetch, setprio).
// ---------------------------------------------------------------------------
__global__ __launch_bounds__(256)
void attn_kernel(const __hip_bfloat16* __restrict__ Q, const __hip_bfloat16* __restrict__ Kx,
                 const __hip_bfloat16* __restrict__ Vt, __hip_bfloat16* __restrict__ out) {
  __shared__ unsigned int Plds[4][2048];  // 8KB per wave
  const int tid = threadIdx.x;
  const int l = tid & 63, w = tid >> 6;
  const int g = l >> 4, q15 = l & 15;
  const int bh = blockIdx.x >> 3;
  const int q0 = (blockIdx.x & 7) * 256 + w * 64;
  const __hip_bfloat16* Qb = Q  + (size_t)bh * TT * HD;
  const __hip_bfloat16* Kb = Kx + (size_t)bh * TT * HD;
  const __hip_bfloat16* Vb = Vt + (size_t)bh * HD * TT;
  unsigned int* Pw = Plds[w];

  u32x4 qf[4][2];
#pragma unroll
  for (int rb = 0; rb < 4; ++rb)
#pragma unroll
    for (int ks = 0; ks < 2; ++ks)
      qf[rb][ks] = *(const u32x4*)(Qb + (size_t)(q0 + rb * 16 + q15) * HD + ks * 32 + g * 8);

  f32x4 acc[4][4];  // [db][rb]
#pragma unroll
  for (int a = 0; a < 4; ++a)
#pragma unroll
    for (int b = 0; b < 4; ++b) acc[a][b] = (f32x4)0.0f;
  float mstat[4] = {-3e38f, -3e38f, -3e38f, -3e38f};
  float lstat[4] = {0.f, 0.f, 0.f, 0.f};

  u32x4 kf[2][4];
#pragma unroll
  for (int cb = 0; cb < 4; ++cb)
#pragma unroll
    for (int ks = 0; ks < 2; ++ks)
      kf[ks][cb] = *(const u32x4*)(Kb + (size_t)(cb * 16 + q15) * HD + ks * 32 + g * 8);

  for (int s0 = 0; s0 < TT; s0 += 64) {
    f32x4 st[4][4];  // [cb][rb] = S^T (exp2-domain logits)
#pragma unroll
    for (int a = 0; a < 4; ++a)
#pragma unroll
      for (int b = 0; b < 4; ++b) st[a][b] = (f32x4)0.0f;
    __builtin_amdgcn_s_setprio(1);
#pragma unroll
    for (int ks = 0; ks < 2; ++ks)
#pragma unroll
      for (int cb = 0; cb < 4; ++cb)
#pragma unroll
        for (int rb = 0; rb < 4; ++rb) MFMA16(st[cb][rb], kf[ks][cb], qf[rb][ks]);
    __builtin_amdgcn_s_setprio(0);
    // prefetch next K tile (kf dead after QK^T) — hides under softmax+PV
    if (s0 + 64 < TT) {
#pragma unroll
      for (int cb = 0; cb < 4; ++cb)
#pragma unroll
        for (int ks = 0; ks < 2; ++ks)
          kf[ks][cb] = *(const u32x4*)(Kb + (size_t)(s0 + 64 + cb * 16 + q15) * HD + ks * 32 + g * 8);
    }
#pragma unroll
    for (int rb = 0; rb < 4; ++rb) {
      // row-max tree (v_max3)
      float a0 = fmax3(st[0][rb][0], st[0][rb][1], st[0][rb][2]);
      float a1 = fmax3(st[0][rb][3], st[1][rb][0], st[1][rb][1]);
      float a2 = fmax3(st[1][rb][2], st[1][rb][3], st[2][rb][0]);
      float a3 = fmax3(st[2][rb][1], st[2][rb][2], st[2][rb][3]);
      float a4 = fmax3(st[3][rb][0], st[3][rb][1], st[3][rb][2]);
      float pm = fmax3(fmax3(a0, a1, a2), a3, fmax3(a4, st[3][rb][3], a0));
      pm = fmaxf(pm, __shfl_xor(pm, 16));
      pm = fmaxf(pm, __shfl_xor(pm, 32));
      // defer-max: only rescale when the running max grows by > 8 (log2)
      if (!__all(pm <= mstat[rb] + 8.0f)) {
        const float mnew = fmaxf(mstat[rb], pm);
        const float corr = fexp2(mstat[rb] - mnew);
        mstat[rb] = mnew;
        lstat[rb] *= corr;
#pragma unroll
        for (int db = 0; db < 4; ++db)
#pragma unroll
          for (int i = 0; i < 4; ++i) acc[db][rb][i] *= corr;
      }
      const float mcur = mstat[rb];
      float rs = 0.f;
      const int row = rb * 16 + q15;
      const int rx = row & 7;
#pragma unroll
      for (int cb = 0; cb < 4; ++cb) {
        const float p0 = fexp2(st[cb][rb][0] - mcur);
        const float p1 = fexp2(st[cb][rb][1] - mcur);
        const float p2 = fexp2(st[cb][rb][2] - mcur);
        const float p3 = fexp2(st[cb][rb][3] - mcur);
        rs += (p0 + p1) + (p2 + p3);
        const int seg = (cb * 2 + (g >> 1)) ^ rx;
        u32x2 pk = {cvtpk(p0, p1), cvtpk(p2, p3)};
        *(u32x2*)(Pw + row * 32 + seg * 4 + (g & 1) * 2) = pk;
      }
      rs += __shfl_xor(rs, 16);
      rs += __shfl_xor(rs, 32);
      lstat[rb] += rs;
    }
    // V loads batched (independent of P write settling)
    u32x4 vf[2][4];
#pragma unroll
    for (int ks2 = 0; ks2 < 2; ++ks2)
#pragma unroll
      for (int db = 0; db < 4; ++db)
        vf[ks2][db] = *(const u32x4*)(Vb + (size_t)(db * 16 + q15) * TT + s0 + ks2 * 32 + g * 8);
    u32x4 pf[2][4];
#pragma unroll
    for (int ks2 = 0; ks2 < 2; ++ks2)
#pragma unroll
      for (int rb = 0; rb < 4; ++rb) {
        const int row = rb * 16 + q15;
        const int seg = (ks2 * 4 + g) ^ (row & 7);
        pf[ks2][rb] = *(const u32x4*)(Pw + row * 32 + seg * 4);
      }
    __builtin_amdgcn_s_setprio(1);
#pragma unroll
    for (int ks2 = 0; ks2 < 2; ++ks2)
#pragma unroll
      for (int db = 0; db < 4; ++db)
#pragma unroll
        for (int rb = 0; rb < 4; ++rb) MFMA16(acc[db][rb], vf[ks2][db], pf[ks2][rb]);
    __builtin_amdgcn_s_setprio(0);
  }
  const int b = bh >> 5, hh = bh & 31;
#pragma unroll
  for (int rb = 0; rb < 4; ++rb) {
    const float inv = 1.0f / lstat[rb];
    const size_t trow = (size_t)(b * TT + q0 + rb * 16 + q15);
#pragma unroll
    for (int db = 0; db < 4; ++db) {
      u32x2 pk = {cvtpk(acc[db][rb][0] * inv, acc[db][rb][1] * inv),
                  cvtpk(acc[db][rb][2] * inv, acc[db][rb][3] * inv)};
      *(u32x2*)(out + trow * DIM + hh * 64 + db * 16 + g * 4) = pk;
    }
  }
}

// ---------------------------------------------------------------------------
extern "C" void kernel_launch(void* const* d_in, const int* in_sizes, int n_in,
                              void* d_out, int out_size, void* d_ws, size_t ws_size,
                              hipStream_t stream) {
  (void)in_sizes; (void)n_in; (void)out_size; (void)ws_size;
  const float* x     = (const float*)d_in[0];
  const float* w_qkv = (const float*)d_in[1];
  const float* b_qkv = (const float*)d_in[2];
  const float* w_o   = (const float*)d_in[3];
  const float* b_o   = (const float*)d_in[4];
  const float* g1    = (const float*)d_in[5];
  const float* be1   = (const float*)d_in[6];
  const float* w1    = (const float*)d_in[7];
  const float* b1    = (const float*)d_in[8];
  const float* w2    = (const float*)d_in[9];
  const float* b2    = (const float*)d_in[10];
  const float* g2    = (const float*)d_in[11];
  const float* be2   = (const float*)d_in[12];

  char* ws = (char*)d_ws;
  size_t off = 0;
  auto alloc = [&](size_t bytes) {
    void* p = ws + off;
    off += (bytes + 255) & ~(size_t)255;
    return p;
  };
  __hip_bfloat16* WqkvT = (__hip_bfloat16*)alloc((size_t)6144 * 2048 * 2);  // 24MB
  __hip_bfloat16* WoT   = (__hip_bfloat16*)alloc((size_t)2048 * 2048 * 2);  //  8MB
  __hip_bfloat16* W1T   = (__hip_bfloat16*)alloc((size_t)8192 * 2048 * 2);  // 32MB
  __hip_bfloat16* W2T   = (__hip_bfloat16*)alloc((size_t)2048 * 8192 * 2);  // 32MB
  __hip_bfloat16* hbuf  = (__hip_bfloat16*)alloc((size_t)MM * DIM * 2);
  float*          xres  = (float*)alloc((size_t)MM * DIM * 4);
  __hip_bfloat16* Qb    = (__hip_bfloat16*)alloc((size_t)MM * DIM * 2);
  __hip_bfloat16* Kb    = (__hip_bfloat16*)alloc((size_t)MM * DIM * 2);
  __hip_bfloat16* Vtb   = (__hip_bfloat16*)alloc((size_t)MM * DIM * 2);
  __hip_bfloat16* attno = (__hip_bfloat16*)alloc((size_t)MM * DIM * 2);
  __hip_bfloat16* f1    = Qb;  // FFN hidden aliases Q/K/Vt/attno (dead then)
  // split-K bf16 partials (16.8MB each) alias WqkvT (dead by FFN2)
  __hip_bfloat16* p0 = (__hip_bfloat16*)ws;
  __hip_bfloat16* p1 = (__hip_bfloat16*)(ws + (size_t)MM * DIM * 2);

  const dim3 tb(16, 16);
  transpose_cvt<<<dim3(6144 / 32, 2048 / 32), tb, 0, stream>>>(w_qkv, WqkvT, 2048, 6144);
  transpose_cvt<<<dim3(2048 / 32, 2048 / 32), tb, 0, stream>>>(w_o, WoT, 2048, 2048);
  transpose_cvt<<<dim3(8192 / 32, 2048 / 32), tb, 0, stream>>>(w1, W1T, 2048, 8192);
  transpose_cvt<<<dim3(2048 / 32, 8192 / 32), tb, 0, stream>>>(w2, W2T, 8192, 2048);

  ln_kernel<<<MM, 256, 0, stream>>>(x, g1, be1, hbuf);
  // QKV on the 128^2 kernel (2D x-fast grid): 48x32 = 1536 blocks, 6 exact
  // rounds -> no tail waste.
  gemm_bt<0><<<dim3(6144 / 128, MM / 128), 256, 0, stream>>>(
      hbuf, WqkvT, b_qkv, nullptr, Qb, Kb, Vtb, MM, 6144, 2048);
  attn_kernel<<<512, 256, 0, stream>>>(Qb, Kb, Vtb, attno);
  gemm_bt<1><<<dim3(2048 / 128, MM / 128), 256, 0, stream>>>(
      attno, WoT, b_o, x, xres, nullptr, nullptr, MM, 2048, 2048);
  ln_kernel<<<MM, 256, 0, stream>>>(xres, g2, be2, hbuf);
  gemm256<2><<<dim3((8192 / 256) * (MM / 256)), 512, 0, stream>>>(
      hbuf, W1T, b1, nullptr, f1, nullptr, nullptr, MM, 8192, 2048, 32);
  gemm256<4><<<dim3((2048 / 256) * (MM / 256), 2), 512, 0, stream>>>(
      f1, W2T, nullptr, nullptr, p0, p1, nullptr, MM, 2048, 8192, 64);
  combine2<<<(MM * DIM) / 2048, 256, 0, stream>>>(p0, p1, b2, xres, (float*)d_out);
}